// Round 1
// baseline (32366.760 us; speedup 1.0000x reference)
//
#include <hip/hip_runtime.h>
#include <math.h>

#define S_LEN 512
#define BATCH 64
#define HID   512
#define TPB   256
#define NWG   256

// workspace layout (bytes)
#define BAR_BYTES   4096
#define HBUF_BYTES  (HID*BATCH*4)                 // 131072 per h buffer
#define A_OFF       BAR_BYTES
#define B_OFF       (A_OFF + 2*HBUF_BYTES)
#define XE_OFF      (B_OFF + 2*HBUF_BYTES)        // 528384
#define XE_BYTES    ((size_t)S_LEN*64*BATCH*16)   // 33554432 (pre-gathered embeddings)

__device__ __forceinline__ float sigmoid_f(float v){ return 1.0f/(1.0f + expf(-v)); }

// Pre-gather embeddings into xe[t][k4][b] (float4-packed along k), pad row zeroed.
__global__ void gather_xe_kernel(const int* __restrict__ x,
                                 const float* __restrict__ emb,
                                 float4* __restrict__ xe4)
{
  int idx = blockIdx.x * TPB + threadIdx.x;   // 2,097,152 total
  int b  = idx & 63;
  int k4 = (idx >> 6) & 63;
  int t  = idx >> 12;
  int tok = x[b * S_LEN + t];
  float4 v = make_float4(0.f, 0.f, 0.f, 0.f);
  if (tok != 0) v = ((const float4*)emb)[(size_t)tok * 64 + k4];
  xe4[idx] = v;
}

// Two-level monotonic grid barrier: 16 leaf counters (16 WGs each) -> root.
// Counters live in ws (zeroed each call). Device-scope atomics + agent fences
// give cross-XCD visibility of the h-state written before the barrier.
__device__ __forceinline__ void barrier_tick(int* bar, int wg, int tid, int phase)
{
  __syncthreads();                       // drains each wave's vmcnt (stores in L2)
  if (tid == 0){
    __builtin_amdgcn_fence(__ATOMIC_RELEASE, "agent");   // write-back L2
    int* leaf = bar + 32 + (wg >> 4) * 32;               // 128B-separated lines
    int old = __hip_atomic_fetch_add(leaf, 1, __ATOMIC_ACQ_REL, __HIP_MEMORY_SCOPE_AGENT);
    if (old == phase * 16 + 15){
      __hip_atomic_fetch_add(bar, 1, __ATOMIC_ACQ_REL, __HIP_MEMORY_SCOPE_AGENT);
    }
    const int target = (phase + 1) * 16;
    while (__hip_atomic_load(bar, __ATOMIC_ACQUIRE, __HIP_MEMORY_SCOPE_AGENT) < target){
      __builtin_amdgcn_s_sleep(2);
    }
    __builtin_amdgcn_fence(__ATOMIC_ACQUIRE, "agent");   // invalidate stale cache
  }
  __syncthreads();
}

// Accumulate 3 gate dot-products from a [k4][b] float4-packed source (coalesced:
// lane = batch). Weight reads are wave-uniform LDS (broadcast, conflict-free).
__device__ __forceinline__ void accum_vec(const float4* __restrict__ xin,
                                          const float4* __restrict__ w0,
                                          const float4* __restrict__ w1,
                                          const float4* __restrict__ w2,
                                          int n4, int lane,
                                          float& ar, float& az, float& an)
{
  #pragma unroll 4
  for (int k = 0; k < n4; ++k){
    float4 xv = xin[k * 64 + lane];
    float4 wr = w0[k], wz = w1[k], wn = w2[k];
    ar = fmaf(xv.x, wr.x, ar); az = fmaf(xv.x, wz.x, az); an = fmaf(xv.x, wn.x, an);
    ar = fmaf(xv.y, wr.y, ar); az = fmaf(xv.y, wz.y, az); an = fmaf(xv.y, wn.y, an);
    ar = fmaf(xv.z, wr.z, ar); az = fmaf(xv.z, wz.z, az); an = fmaf(xv.z, wn.z, an);
    ar = fmaf(xv.w, wr.w, ar); az = fmaf(xv.w, wz.w, az); an = fmaf(xv.w, wn.w, an);
  }
}

// Fallback layer-0 input accumulation: gather emb rows directly (used only when
// ws is too small to hold the pre-gathered xe).
__device__ __forceinline__ void accum_emb(const int* __restrict__ x,
                                          const float* __restrict__ emb, int t,
                                          const float4* __restrict__ w0,
                                          const float4* __restrict__ w1,
                                          const float4* __restrict__ w2,
                                          int lane, float& ar, float& az, float& an)
{
  int tok = x[lane * S_LEN + t];
  const float4* erow = (const float4*)emb + (size_t)tok * 64;
  float m = (tok != 0) ? 1.0f : 0.0f;     // PAD row behaves as zeros
  #pragma unroll 4
  for (int k = 0; k < 64; ++k){
    float4 xv = erow[k];
    float xx = xv.x*m, xy = xv.y*m, xz = xv.z*m, xw = xv.w*m;
    float4 wr = w0[k], wz = w1[k], wn = w2[k];
    ar = fmaf(xx, wr.x, ar); az = fmaf(xx, wz.x, az); an = fmaf(xx, wn.x, an);
    ar = fmaf(xy, wr.y, ar); az = fmaf(xy, wz.y, az); an = fmaf(xy, wn.y, an);
    ar = fmaf(xz, wr.z, ar); az = fmaf(xz, wz.z, az); an = fmaf(xz, wn.z, an);
    ar = fmaf(xw, wr.w, ar); az = fmaf(xw, wz.w, az); an = fmaf(xw, wn.w, an);
  }
}

__device__ __forceinline__ void finish_store(const float4* __restrict__ hprev,
                                             float ar, float az, float anx, float anh,
                                             int lane, int j, float4* __restrict__ hout)
{
  float r  = sigmoid_f(ar);
  float zz = sigmoid_f(az);
  float n  = tanhf(fmaf(r, anh, anx));         // n = tanh(xn + r*hn), hn incl. b_hh
  int fi = ((j >> 2) * 64 + lane) * 4 + (j & 3);
  float hp = ((const float*)hprev)[fi];
  ((float*)hout)[fi] = fmaf(zz, hp - n, n);    // (1-z)*n + z*h
}

// Persistent kernel: 256 WGs. WG<128 -> layer0 slice, WG>=128 -> layer1 slice.
// Each WG owns 4 hidden units (j0..j0+3) x 64 batches; weights for its slice
// pinned in LDS. Pipeline skew: tick t computes L0 step t and L1 step t-1.
__global__ __launch_bounds__(TPB) void gru_persist_kernel(
    const int*   __restrict__ x,    const float* __restrict__ emb,
    const float* __restrict__ Wih0, const float* __restrict__ Whh0,
    const float* __restrict__ bih0, const float* __restrict__ bhh0,
    const float* __restrict__ Wih1, const float* __restrict__ Whh1,
    const float* __restrict__ bih1, const float* __restrict__ bhh1,
    const float* __restrict__ Wfc,  const float* __restrict__ bfc,
    float* __restrict__ out, int* __restrict__ bar,
    float4* __restrict__ A0, float4* __restrict__ A1,
    float4* __restrict__ B0, float4* __restrict__ B1,
    const float4* __restrict__ xe4, int use_xe)
{
  __shared__ float4 wlds[3072];   // 48 KB: [wave][gate][256 f4]; input part then hidden part

  const int tid  = threadIdx.x;
  const int wg   = blockIdx.x;
  const int lane = tid & 63;      // batch index
  const int wave = tid >> 6;      // which of this WG's 4 hidden units
  const bool isL1 = (wg >= 128);
  const int j0   = (isL1 ? wg - 128 : wg) * 4;
  const int kin4 = isL1 ? 128 : 64;          // input K in float4s (E=256 or H=512)
  const float* Wih = isL1 ? Wih1 : Wih0;
  const float* Whh = isL1 ? Whh1 : Whh0;

  // ---- one-time: load this WG's weight slice into LDS (coalesced f4 copies) ----
  const int per = 3 * (kin4 + 128);          // f4 per wave (3 gates x (Kin + 512h))
  for (int idx = tid; idx < 4 * per; idx += TPB){
    int w = idx / per, rem = idx - w * per;
    int g = rem / (kin4 + 128), k = rem - g * (kin4 + 128);
    int row = g * HID + j0 + w;              // gate-major rows: r=0..511, z=512.., n=1024..
    float4 v;
    if (k < kin4) v = ((const float4*)Wih)[(size_t)row * kin4 + k];
    else          v = ((const float4*)Whh)[(size_t)row * 128 + (k - kin4)];
    wlds[(w * 3 + g) * 256 + k] = v;
  }
  __syncthreads();

  const int j = j0 + wave;
  const float* bih = isL1 ? bih1 : bih0;
  const float* bhh = isL1 ? bhh1 : bhh0;
  const float br  = bih[j]        + bhh[j];
  const float bz  = bih[j + 512]  + bhh[j + 512];
  const float bnx = bih[j + 1024];
  const float bnh = bhh[j + 1024];

  const float4* w0 = &wlds[(wave * 3 + 0) * 256];
  const float4* w1 = &wlds[(wave * 3 + 1) * 256];
  const float4* w2 = &wlds[(wave * 3 + 2) * 256];

  float4* A[2] = {A0, A1};   // layer0 h, ping-pong, [k4][b] f4-packed
  float4* B[2] = {B0, B1};   // layer1 h

  for (int t = 0; t <= S_LEN; ++t){
    if (!isL1){
      if (t < S_LEN){
        const float4* hprev = A[(t + 1) & 1];        // h0_{t-1}
        float ar = br, az = bz, anx = bnx, anh = bnh;
        if (use_xe) accum_vec(xe4 + (size_t)t * 4096, w0, w1, w2, 64, lane, ar, az, anx);
        else        accum_emb(x, emb, t, w0, w1, w2, lane, ar, az, anx);
        accum_vec(hprev, w0 + 64, w1 + 64, w2 + 64, 128, lane, ar, az, anh);
        finish_store(hprev, ar, az, anx, anh, lane, j, A[t & 1]);
      }
    } else if (t >= 1){
      const int u = t - 1;                           // layer1 step index
      const float4* xin   = A[u & 1];                // layer0 output h0_u
      const float4* hprev = B[(u + 1) & 1];          // h1_{u-1}
      float ar = br, az = bz, anx = bnx, anh = bnh;
      accum_vec(xin,   w0,       w1,       w2,       128, lane, ar, az, anx);
      accum_vec(hprev, w0 + 128, w1 + 128, w2 + 128, 128, lane, ar, az, anh);
      finish_store(hprev, ar, az, anx, anh, lane, j, B[u & 1]);
    }
    barrier_tick(bar, wg, tid, t);
  }

  // ---- epilogue: out[b] = sigmoid(h1_final . W_fc + b_fc); h1_final in B[1] ----
  if (wg == 0 && wave == 0){
    float acc = bfc[0];
    const float4* h1 = B[1];
    const float4* wf = (const float4*)Wfc;
    #pragma unroll 4
    for (int k = 0; k < 128; ++k){
      float4 hv = h1[k * 64 + lane];
      float4 wv = wf[k];
      acc = fmaf(hv.x, wv.x, acc); acc = fmaf(hv.y, wv.y, acc);
      acc = fmaf(hv.z, wv.z, acc); acc = fmaf(hv.w, wv.w, acc);
    }
    out[lane] = sigmoid_f(acc);
  }
}

extern "C" void kernel_launch(void* const* d_in, const int* in_sizes, int n_in,
                              void* d_out, int out_size, void* d_ws, size_t ws_size,
                              hipStream_t stream)
{
  (void)in_sizes; (void)n_in; (void)out_size;
  const int*   x    = (const int*)  d_in[0];
  const float* emb  = (const float*)d_in[1];
  const float* Wih0 = (const float*)d_in[2];
  const float* Whh0 = (const float*)d_in[3];
  const float* bih0 = (const float*)d_in[4];
  const float* bhh0 = (const float*)d_in[5];
  const float* Wih1 = (const float*)d_in[6];
  const float* Whh1 = (const float*)d_in[7];
  const float* bih1 = (const float*)d_in[8];
  const float* bhh1 = (const float*)d_in[9];
  const float* Wfc  = (const float*)d_in[10];
  const float* bfc  = (const float*)d_in[11];
  float* out = (float*)d_out;

  char* ws = (char*)d_ws;
  int*    bar = (int*)ws;
  float4* A0  = (float4*)(ws + A_OFF);
  float4* A1  = (float4*)(ws + A_OFF + HBUF_BYTES);
  float4* B0  = (float4*)(ws + B_OFF);
  float4* B1  = (float4*)(ws + B_OFF + HBUF_BYTES);
  float4* xe4 = (float4*)(ws + XE_OFF);
  const int use_xe = (ws_size >= (size_t)XE_OFF + XE_BYTES) ? 1 : 0;

  // zero barrier counters + h ping-pong buffers (ws is poisoned before each call)
  hipMemsetAsync(ws, 0, XE_OFF, stream);

  if (use_xe){
    gather_xe_kernel<<<(S_LEN * 64 * BATCH) / TPB, TPB, 0, stream>>>(x, emb, xe4);
  }

  gru_persist_kernel<<<NWG, TPB, 0, stream>>>(
      x, emb, Wih0, Whh0, bih0, bhh0, Wih1, Whh1, bih1, bhh1, Wfc, bfc,
      out, bar, A0, A1, B0, B1, xe4, use_xe);
}

// Round 2
// 11404.287 us; speedup vs baseline: 2.8381x; 2.8381x over previous
//
#include <hip/hip_runtime.h>
#include <math.h>

#define S_LEN 512
#define BATCH 64
#define HID   512
#define TPB   256
#define NWG   256

// ---------------- old (fence-based) fallback workspace layout ----------------
#define BAR_BYTES   4096
#define HBUF_BYTES  (HID*BATCH*4)                 // 131072 per h buffer
#define A_OFF       BAR_BYTES
#define B_OFF       (A_OFF + 2*HBUF_BYTES)
#define XE_OFF      (B_OFF + 2*HBUF_BYTES)        // 528384
#define XE_BYTES    ((size_t)S_LEN*64*BATCH*16)   // 33554432

// ---------------- fast-path workspace layout (full h rotation) ----------------
#define HBUF      131072L
#define LEAF0_OFF 0L
#define LEAF1_OFF 786432L
#define ROOT0_OFF 1572864L
#define ROOT1_OFF 1703936L
#define ZSLOT_OFF 2097152L                 // 128KB zero h slot (memset)
#define H0F_OFF   2228224L                 // 512 x 128KB
#define H1F_OFF   (H0F_OFF + 512L*HBUF)    // 69337088
#define XEF_OFF   (H1F_OFF + 512L*HBUF)    // 136445952
#define FAST_BASE XEF_OFF
#define FAST_XE   (XEF_OFF + 33554432L)    // 170000384

__device__ __forceinline__ float sigmoid_f(float v){ return 1.0f/(1.0f + expf(-v)); }

// Pre-gather embeddings into xe[t][k4][b] (float4-packed along k), pad row zeroed.
__global__ void gather_xe_kernel(const int* __restrict__ x,
                                 const float* __restrict__ emb,
                                 float4* __restrict__ xe4)
{
  int idx = blockIdx.x * TPB + threadIdx.x;   // 2,097,152 total
  int b  = idx & 63;
  int k4 = (idx >> 6) & 63;
  int t  = idx >> 12;
  int tok = x[b * S_LEN + t];
  float4 v = make_float4(0.f, 0.f, 0.f, 0.f);
  if (tok != 0) v = ((const float4*)emb)[(size_t)tok * 64 + k4];
  xe4[idx] = v;
}

// ---------------- device-coherent primitives (NO cache-flush fences) ----------------
// Relaxed agent-scope atomics compile to sc0/sc1 (Infinity-Cache-coherent) ops:
// no buffer_wbl2 / buffer_inv, compiler-tracked vmcnt. Full h rotation means
// every h address is write-once-then-read, so plain cached consumer loads are
// never stale; producers write through to IC and drain vmcnt before signaling.
__device__ __forceinline__ void store_wt(float* p, float v){
  __hip_atomic_store(p, v, __ATOMIC_RELAXED, __HIP_MEMORY_SCOPE_AGENT);
}
__device__ __forceinline__ void wait_ctr(int* p, int target){
  while (__hip_atomic_load(p, __ATOMIC_RELAXED, __HIP_MEMORY_SCOPE_AGENT) < target)
    __builtin_amdgcn_s_sleep(1);
}
__device__ __forceinline__ void signal_ctr(char* ws, long leaf_off, long root_off,
                                           int t, int lwg){
  int* leaf = (int*)(ws + leaf_off + ((long)t*8 + (lwg>>4))*128);
  int old = __hip_atomic_fetch_add(leaf, 1, __ATOMIC_RELAXED, __HIP_MEMORY_SCOPE_AGENT);
  if (old == 15){
    int* root = (int*)(ws + root_off + (long)t*128);
    __hip_atomic_fetch_add(root, 1, __ATOMIC_RELAXED, __HIP_MEMORY_SCOPE_AGENT);
  }
}

// ---------------- shared accumulation helpers ----------------
__device__ __forceinline__ void accum_vec(const float4* __restrict__ xin,
                                          const float4* __restrict__ w0,
                                          const float4* __restrict__ w1,
                                          const float4* __restrict__ w2,
                                          int n4, int lane,
                                          float& ar, float& az, float& an)
{
  #pragma unroll 4
  for (int k = 0; k < n4; ++k){
    float4 xv = xin[k * 64 + lane];
    float4 wr = w0[k], wz = w1[k], wn = w2[k];
    ar = fmaf(xv.x, wr.x, ar); az = fmaf(xv.x, wz.x, az); an = fmaf(xv.x, wn.x, an);
    ar = fmaf(xv.y, wr.y, ar); az = fmaf(xv.y, wz.y, az); an = fmaf(xv.y, wn.y, an);
    ar = fmaf(xv.z, wr.z, ar); az = fmaf(xv.z, wz.z, az); an = fmaf(xv.z, wn.z, an);
    ar = fmaf(xv.w, wr.w, ar); az = fmaf(xv.w, wz.w, az); an = fmaf(xv.w, wn.w, an);
  }
}

__device__ __forceinline__ void accum_emb(const int* __restrict__ x,
                                          const float* __restrict__ emb, int t,
                                          const float4* __restrict__ w0,
                                          const float4* __restrict__ w1,
                                          const float4* __restrict__ w2,
                                          int lane, float& ar, float& az, float& an)
{
  int tok = x[lane * S_LEN + t];
  const float4* erow = (const float4*)emb + (size_t)tok * 64;
  float m = (tok != 0) ? 1.0f : 0.0f;
  #pragma unroll 4
  for (int k = 0; k < 64; ++k){
    float4 xv = erow[k];
    float xx = xv.x*m, xy = xv.y*m, xz = xv.z*m, xw = xv.w*m;
    float4 wr = w0[k], wz = w1[k], wn = w2[k];
    ar = fmaf(xx, wr.x, ar); az = fmaf(xx, wz.x, az); an = fmaf(xx, wn.x, an);
    ar = fmaf(xy, wr.y, ar); az = fmaf(xy, wz.y, az); an = fmaf(xy, wn.y, an);
    ar = fmaf(xz, wr.z, ar); az = fmaf(xz, wz.z, az); an = fmaf(xz, wn.z, an);
    ar = fmaf(xw, wr.w, ar); az = fmaf(xw, wz.w, az); an = fmaf(xw, wn.w, an);
  }
}

// ---------------- weight staging into LDS (shared by both kernels) ----------------
__device__ __forceinline__ void stage_weights(float4* wlds, int tid, int j0, int kin4,
                                              const float* Wih, const float* Whh)
{
  const int per = 3 * (kin4 + 128);
  for (int idx = tid; idx < 4 * per; idx += TPB){
    int w = idx / per, rem = idx - w * per;
    int g = rem / (kin4 + 128), k = rem - g * (kin4 + 128);
    int row = g * HID + j0 + w;
    float4 v;
    if (k < kin4) v = ((const float4*)Wih)[(size_t)row * kin4 + k];
    else          v = ((const float4*)Whh)[(size_t)row * 128 + (k - kin4)];
    wlds[(w * 3 + g) * 256 + k] = v;
  }
}

// =====================================================================
// FAST PATH: full h rotation + per-tick RAW counters, no cache fences.
// WGs 0-127: layer 0 (4 hidden units each). WGs 128-255: layer 1.
// =====================================================================
__global__ __launch_bounds__(TPB) void gru_fast_kernel(
    const int*   __restrict__ x,    const float* __restrict__ emb,
    const float* __restrict__ Wih0, const float* __restrict__ Whh0,
    const float* __restrict__ bih0, const float* __restrict__ bhh0,
    const float* __restrict__ Wih1, const float* __restrict__ Whh1,
    const float* __restrict__ bih1, const float* __restrict__ bhh1,
    const float* __restrict__ Wfc,  const float* __restrict__ bfc,
    float* __restrict__ out, char* __restrict__ ws, int use_xe)
{
  __shared__ float4 wlds[3072];   // 48 KB

  const int tid  = threadIdx.x;
  const int wg   = blockIdx.x;
  const int lane = tid & 63;      // batch index
  const int wave = tid >> 6;      // hidden unit within this WG's 4-slice
  const bool isL1 = (wg >= 128);
  const int lwg  = isL1 ? wg - 128 : wg;
  const int j0   = lwg * 4;
  const int kin4 = isL1 ? 128 : 64;

  stage_weights(wlds, tid, j0, kin4, isL1 ? Wih1 : Wih0, isL1 ? Whh1 : Whh0);
  __syncthreads();

  const int j = j0 + wave;
  const float* bih = isL1 ? bih1 : bih0;
  const float* bhh = isL1 ? bhh1 : bhh0;
  const float br  = bih[j]        + bhh[j];
  const float bz  = bih[j + 512]  + bhh[j + 512];
  const float bnx = bih[j + 1024];
  const float bnh = bhh[j + 1024];

  const float4* w0 = &wlds[(wave * 3 + 0) * 256];
  const float4* w1 = &wlds[(wave * 3 + 1) * 256];
  const float4* w2 = &wlds[(wave * 3 + 2) * 256];

  const float4* zslot = (const float4*)(ws + ZSLOT_OFF);
  const int fi = (lwg * 64 + lane) * 4 + wave;   // (j>>2)==lwg, (j&3)==wave

  if (!isL1){
    for (int t = 0; t < S_LEN; ++t){
      if (tid == 0 && t > 0)
        wait_ctr((int*)(ws + ROOT0_OFF + (long)(t-1)*128), 8);
      __syncthreads();
      const float4* hprev = t ? (const float4*)(ws + H0F_OFF + (long)(t-1)*HBUF) : zslot;
      float ar = br, az = bz, anx = bnx, anh = bnh;
      if (use_xe) accum_vec((const float4*)(ws + XEF_OFF + (long)t*65536),
                            w0, w1, w2, 64, lane, ar, az, anx);
      else        accum_emb(x, emb, t, w0, w1, w2, lane, ar, az, anx);
      accum_vec(hprev, w0 + 64, w1 + 64, w2 + 64, 128, lane, ar, az, anh);
      float r  = sigmoid_f(ar);
      float zz = sigmoid_f(az);
      float n  = tanhf(fmaf(r, anh, anx));
      float hp = ((const float*)hprev)[fi];
      store_wt((float*)(ws + H0F_OFF + (long)t*HBUF) + fi, fmaf(zz, hp - n, n));
      asm volatile("s_waitcnt vmcnt(0)" ::: "memory");   // per-wave drain to IC
      __syncthreads();
      if (tid == 0) signal_ctr(ws, LEAF0_OFF, ROOT0_OFF, t, lwg);
    }
  } else {
    for (int u = 0; u < S_LEN; ++u){
      if (tid == 0){
        wait_ctr((int*)(ws + ROOT0_OFF + (long)u*128), 8);          // h0_u ready
        if (u > 0) wait_ctr((int*)(ws + ROOT1_OFF + (long)(u-1)*128), 8);
      }
      __syncthreads();
      const float4* xin   = (const float4*)(ws + H0F_OFF + (long)u*HBUF);
      const float4* hprev = u ? (const float4*)(ws + H1F_OFF + (long)(u-1)*HBUF) : zslot;
      float ar = br, az = bz, anx = bnx, anh = bnh;
      accum_vec(xin,   w0,       w1,       w2,       128, lane, ar, az, anx);
      accum_vec(hprev, w0 + 128, w1 + 128, w2 + 128, 128, lane, ar, az, anh);
      float r  = sigmoid_f(ar);
      float zz = sigmoid_f(az);
      float n  = tanhf(fmaf(r, anh, anx));
      float hp = ((const float*)hprev)[fi];
      store_wt((float*)(ws + H1F_OFF + (long)u*HBUF) + fi, fmaf(zz, hp - n, n));
      asm volatile("s_waitcnt vmcnt(0)" ::: "memory");
      __syncthreads();
      if (tid == 0) signal_ctr(ws, LEAF1_OFF, ROOT1_OFF, u, lwg);
    }
    if (wg == 128){
      if (tid == 0) wait_ctr((int*)(ws + ROOT1_OFF + 511L*128), 8);
      __syncthreads();
      if (wave == 0){
        float acc = bfc[0];
        const float4* h1 = (const float4*)(ws + H1F_OFF + 511L*HBUF);
        const float4* wf = (const float4*)Wfc;
        #pragma unroll 4
        for (int k = 0; k < 128; ++k){
          float4 hv = h1[k * 64 + lane];
          float4 wv = wf[k];
          acc = fmaf(hv.x, wv.x, acc); acc = fmaf(hv.y, wv.y, acc);
          acc = fmaf(hv.z, wv.z, acc); acc = fmaf(hv.w, wv.w, acc);
        }
        out[lane] = sigmoid_f(acc);
      }
    }
  }
}

// =====================================================================
// FALLBACK (R1 fence-based path) — used only when ws is too small.
// =====================================================================
__device__ __forceinline__ void barrier_tick(int* bar, int wg, int tid, int phase)
{
  __syncthreads();
  if (tid == 0){
    __builtin_amdgcn_fence(__ATOMIC_RELEASE, "agent");
    int* leaf = bar + 32 + (wg >> 4) * 32;
    int old = __hip_atomic_fetch_add(leaf, 1, __ATOMIC_ACQ_REL, __HIP_MEMORY_SCOPE_AGENT);
    if (old == phase * 16 + 15){
      __hip_atomic_fetch_add(bar, 1, __ATOMIC_ACQ_REL, __HIP_MEMORY_SCOPE_AGENT);
    }
    const int target = (phase + 1) * 16;
    while (__hip_atomic_load(bar, __ATOMIC_ACQUIRE, __HIP_MEMORY_SCOPE_AGENT) < target){
      __builtin_amdgcn_s_sleep(2);
    }
    __builtin_amdgcn_fence(__ATOMIC_ACQUIRE, "agent");
  }
  __syncthreads();
}

__device__ __forceinline__ void finish_store(const float4* __restrict__ hprev,
                                             float ar, float az, float anx, float anh,
                                             int lane, int j, float4* __restrict__ hout)
{
  float r  = sigmoid_f(ar);
  float zz = sigmoid_f(az);
  float n  = tanhf(fmaf(r, anh, anx));
  int fi = ((j >> 2) * 64 + lane) * 4 + (j & 3);
  float hp = ((const float*)hprev)[fi];
  ((float*)hout)[fi] = fmaf(zz, hp - n, n);
}

__global__ __launch_bounds__(TPB) void gru_persist_kernel(
    const int*   __restrict__ x,    const float* __restrict__ emb,
    const float* __restrict__ Wih0, const float* __restrict__ Whh0,
    const float* __restrict__ bih0, const float* __restrict__ bhh0,
    const float* __restrict__ Wih1, const float* __restrict__ Whh1,
    const float* __restrict__ bih1, const float* __restrict__ bhh1,
    const float* __restrict__ Wfc,  const float* __restrict__ bfc,
    float* __restrict__ out, int* __restrict__ bar,
    float4* __restrict__ A0, float4* __restrict__ A1,
    float4* __restrict__ B0, float4* __restrict__ B1,
    const float4* __restrict__ xe4, int use_xe)
{
  __shared__ float4 wlds[3072];
  const int tid  = threadIdx.x;
  const int wg   = blockIdx.x;
  const int lane = tid & 63;
  const int wave = tid >> 6;
  const bool isL1 = (wg >= 128);
  const int j0   = (isL1 ? wg - 128 : wg) * 4;
  const int kin4 = isL1 ? 128 : 64;

  stage_weights(wlds, tid, j0, kin4, isL1 ? Wih1 : Wih0, isL1 ? Whh1 : Whh0);
  __syncthreads();

  const int j = j0 + wave;
  const float* bih = isL1 ? bih1 : bih0;
  const float* bhh = isL1 ? bhh1 : bhh0;
  const float br  = bih[j]        + bhh[j];
  const float bz  = bih[j + 512]  + bhh[j + 512];
  const float bnx = bih[j + 1024];
  const float bnh = bhh[j + 1024];

  const float4* w0 = &wlds[(wave * 3 + 0) * 256];
  const float4* w1 = &wlds[(wave * 3 + 1) * 256];
  const float4* w2 = &wlds[(wave * 3 + 2) * 256];

  float4* A[2] = {A0, A1};
  float4* B[2] = {B0, B1};

  for (int t = 0; t <= S_LEN; ++t){
    if (!isL1){
      if (t < S_LEN){
        const float4* hprev = A[(t + 1) & 1];
        float ar = br, az = bz, anx = bnx, anh = bnh;
        if (use_xe) accum_vec(xe4 + (size_t)t * 4096, w0, w1, w2, 64, lane, ar, az, anx);
        else        accum_emb(x, emb, t, w0, w1, w2, lane, ar, az, anx);
        accum_vec(hprev, w0 + 64, w1 + 64, w2 + 64, 128, lane, ar, az, anh);
        finish_store(hprev, ar, az, anx, anh, lane, j, A[t & 1]);
      }
    } else if (t >= 1){
      const int u = t - 1;
      const float4* xin   = A[u & 1];
      const float4* hprev = B[(u + 1) & 1];
      float ar = br, az = bz, anx = bnx, anh = bnh;
      accum_vec(xin,   w0,       w1,       w2,       128, lane, ar, az, anx);
      accum_vec(hprev, w0 + 128, w1 + 128, w2 + 128, 128, lane, ar, az, anh);
      finish_store(hprev, ar, az, anx, anh, lane, j, B[u & 1]);
    }
    barrier_tick(bar, wg, tid, t);
  }

  if (wg == 0 && wave == 0){
    float acc = bfc[0];
    const float4* h1 = B[1];
    const float4* wf = (const float4*)Wfc;
    #pragma unroll 4
    for (int k = 0; k < 128; ++k){
      float4 hv = h1[k * 64 + lane];
      float4 wv = wf[k];
      acc = fmaf(hv.x, wv.x, acc); acc = fmaf(hv.y, wv.y, acc);
      acc = fmaf(hv.z, wv.z, acc); acc = fmaf(hv.w, wv.w, acc);
    }
    out[lane] = sigmoid_f(acc);
  }
}

extern "C" void kernel_launch(void* const* d_in, const int* in_sizes, int n_in,
                              void* d_out, int out_size, void* d_ws, size_t ws_size,
                              hipStream_t stream)
{
  (void)in_sizes; (void)n_in; (void)out_size;
  const int*   x    = (const int*)  d_in[0];
  const float* emb  = (const float*)d_in[1];
  const float* Wih0 = (const float*)d_in[2];
  const float* Whh0 = (const float*)d_in[3];
  const float* bih0 = (const float*)d_in[4];
  const float* bhh0 = (const float*)d_in[5];
  const float* Wih1 = (const float*)d_in[6];
  const float* Whh1 = (const float*)d_in[7];
  const float* bih1 = (const float*)d_in[8];
  const float* bhh1 = (const float*)d_in[9];
  const float* Wfc  = (const float*)d_in[10];
  const float* bfc  = (const float*)d_in[11];
  float* out = (float*)d_out;
  char* ws = (char*)d_ws;

  if (ws_size >= (size_t)FAST_BASE){
    const int use_xe = (ws_size >= (size_t)FAST_XE) ? 1 : 0;
    // zero counters + zero-h slot ([0, H0F_OFF) == counters + zslot, contiguous)
    hipMemsetAsync(ws, 0, (size_t)H0F_OFF, stream);
    if (use_xe){
      gather_xe_kernel<<<(S_LEN * 64 * BATCH) / TPB, TPB, 0, stream>>>(
          x, emb, (float4*)(ws + XEF_OFF));
    }
    gru_fast_kernel<<<NWG, TPB, 0, stream>>>(
        x, emb, Wih0, Whh0, bih0, bhh0, Wih1, Whh1, bih1, bhh1, Wfc, bfc,
        out, ws, use_xe);
  } else {
    int*    bar = (int*)ws;
    float4* A0  = (float4*)(ws + A_OFF);
    float4* A1  = (float4*)(ws + A_OFF + HBUF_BYTES);
    float4* B0  = (float4*)(ws + B_OFF);
    float4* B1  = (float4*)(ws + B_OFF + HBUF_BYTES);
    float4* xe4 = (float4*)(ws + XE_OFF);
    const int use_xe = (ws_size >= (size_t)XE_OFF + XE_BYTES) ? 1 : 0;
    hipMemsetAsync(ws, 0, XE_OFF, stream);
    if (use_xe){
      gather_xe_kernel<<<(S_LEN * 64 * BATCH) / TPB, TPB, 0, stream>>>(x, emb, xe4);
    }
    gru_persist_kernel<<<NWG, TPB, 0, stream>>>(
        x, emb, Wih0, Whh0, bih0, bhh0, Wih1, Whh1, bih1, bhh1, Wfc, bfc,
        out, bar, A0, A1, B0, B1, xe4, use_xe);
  }
}

// Round 3
// 7950.979 us; speedup vs baseline: 4.0708x; 1.4343x over previous
//
#include <hip/hip_runtime.h>
#include <math.h>

typedef float v2f __attribute__((ext_vector_type(2)));
typedef float v4f __attribute__((ext_vector_type(4)));

#define S_LEN 512
#define BATCH 64
#define HID   512
#define TPB   256
#define NWG   256

// ---------------- fallback (fence-based) workspace layout ----------------
#define BAR_BYTES   4096
#define HBUF_BYTES  (HID*BATCH*4)
#define A_OFF       BAR_BYTES
#define B_OFF       (A_OFF + 2*HBUF_BYTES)
#define XE_OFF      (B_OFF + 2*HBUF_BYTES)
#define XE_BYTES    ((size_t)S_LEN*64*BATCH*16)

// ---------------- fast-path workspace layout ----------------
// sync: per layer 1MB: leaf[t][8] lines then flag[t][8] lines, 128B each
#define SYNC0     0L
#define SYNC1     (1L<<20)
#define FLAG_OFF  (512L*1024)
#define SLOT      131072L                  // one h snapshot (512x64 f32)
#define H0F_OFF   (2L<<20)                 // 512 slots
#define H1F_OFF   (H0F_OFF + 512L*SLOT)    // 69,206,016
#define XEF_OFF   (H1F_OFF + 512L*SLOT)    // 136,314,880
#define FAST_MIN  XEF_OFF
#define FAST_XE   (XEF_OFF + 33554432L)    // 169,869,312

__device__ __forceinline__ float sigmoid_f(float v){ return 1.0f/(1.0f + expf(-v)); }

__device__ __forceinline__ v2f fma2(v2f a, v2f b, v2f c){
#if __has_builtin(__builtin_elementwise_fma)
  return __builtin_elementwise_fma(a, b, c);
#else
  v2f r; r.x = fmaf(a.x, b.x, c.x); r.y = fmaf(a.y, b.y, c.y); return r;
#endif
}

// coherent write-through f4 store + drain (visible in IC before signaling)
__device__ __forceinline__ void store_f4_coh(void* p, v4f v){
  asm volatile("global_store_dwordx4 %0, %1, off sc0 sc1" :: "v"(p), "v"(v) : "memory");
  asm volatile("s_waitcnt vmcnt(0)" ::: "memory");
}

// Pre-gather embeddings into xe[t][k4][b] (float4-packed along k), pad row zeroed.
__global__ void gather_xe_kernel(const int* __restrict__ x,
                                 const float* __restrict__ emb,
                                 float4* __restrict__ xe4)
{
  int idx = blockIdx.x * TPB + threadIdx.x;
  int b  = idx & 63;
  int k4 = (idx >> 6) & 63;
  int t  = idx >> 12;
  int tok = x[b * S_LEN + t];
  float4 v = make_float4(0.f, 0.f, 0.f, 0.f);
  if (tok != 0) v = ((const float4*)emb)[(size_t)tok * 64 + k4];
  xe4[idx] = v;
}

// ---------------- fast-path sync primitives (relaxed agent atomics only) ----------------
__device__ __forceinline__ void wait_flag(void* p, int target){
  while (__hip_atomic_load((int*)p, __ATOMIC_RELAXED, __HIP_MEMORY_SCOPE_AGENT) < target)
    __builtin_amdgcn_s_sleep(2);
}
__device__ __forceinline__ void signal2(char* ws, long lbase, int t, int lwg){
  int* leaf = (int*)(ws + lbase + ((long)t*8 + (lwg>>4))*128);
  int old = __hip_atomic_fetch_add(leaf, 1, __ATOMIC_RELAXED, __HIP_MEMORY_SCOPE_AGENT);
  if (old == 15){
    char* fb = ws + lbase + FLAG_OFF;
    #pragma unroll
    for (int c = 0; c < 8; ++c)
      __hip_atomic_fetch_add((int*)(fb + ((long)t*8 + c)*128), 1,
                             __ATOMIC_RELAXED, __HIP_MEMORY_SCOPE_AGENT);
  }
}

// K-split accumulation over [k0, k0+n) f4-steps (n multiple of 8), 8-deep
// pipelined global x loads; weights broadcast from LDS; packed-f32 accum.
// a[u*4+c]: c=0 r, 1 z, 2 n-input, 3 n-hidden; c2 selects c for the n gate.
__device__ __forceinline__ void accum_span(const float4* __restrict__ xsrc,
                                           const float4* __restrict__ wl,
                                           int TOT4, int k0, int n,
                                           int lane, int c2, v2f* a)
{
  float4 cur[8], nxt[8];
  #pragma unroll
  for (int i = 0; i < 8; ++i) cur[i] = xsrc[(k0 + i)*64 + lane];
  const int NC = n >> 3;
  for (int c = 0; c < NC; ++c){
    const int kb = k0 + c*8;
    if (c + 1 < NC){
      #pragma unroll
      for (int i = 0; i < 8; ++i) nxt[i] = xsrc[(kb + 8 + i)*64 + lane];
    }
    #pragma unroll
    for (int i = 0; i < 8; ++i){
      const int k = kb + i;
      v2f xlo = {cur[i].x, cur[i].y}, xhi = {cur[i].z, cur[i].w};
      #pragma unroll
      for (int g = 0; g < 3; ++g){
        const int cc = (g == 2) ? c2 : g;
        #pragma unroll
        for (int u = 0; u < 4; ++u){
          float4 wv = wl[(g*4 + u)*TOT4 + k];
          v2f wlo = {wv.x, wv.y}, whi = {wv.z, wv.w};
          a[u*4 + cc] = fma2(xlo, wlo, a[u*4 + cc]);
          a[u*4 + cc] = fma2(xhi, whi, a[u*4 + cc]);
        }
      }
    }
    if (c + 1 < NC){
      #pragma unroll
      for (int i = 0; i < 8; ++i) cur[i] = nxt[i];
    }
  }
}

// =====================================================================
// FAST v2: K-split waves, packed f32, coalesced h stores, flag broadcast.
// WGs 0-127: layer 0, units j0=4*wg. WGs 128-255: layer 1.
// =====================================================================
__global__ __launch_bounds__(TPB) void gru_fast2_kernel(
    const int*   __restrict__ x,    const float* __restrict__ emb,
    const float* __restrict__ Wih0, const float* __restrict__ Whh0,
    const float* __restrict__ bih0, const float* __restrict__ bhh0,
    const float* __restrict__ Wih1, const float* __restrict__ Whh1,
    const float* __restrict__ bih1, const float* __restrict__ bhh1,
    const float* __restrict__ Wfc,  const float* __restrict__ bfc,
    float* __restrict__ out, char* __restrict__ ws, int use_xe)
{
  __shared__ float4 smem[4096];               // 64 KB: [0,3072) weights, [3072,) partials
  float* ps  = (float*)(smem + 3072);         // 16 KB partials [w][16][b]
  float* htr = (float*)(smem + 3072);         // overlaid (extra sync separates uses)

  const int tid  = threadIdx.x;
  const int wg   = blockIdx.x;
  const int lane = tid & 63;                  // batch
  const int wave = tid >> 6;                  // K-slice owner / gate-phase unit
  const bool isL1 = (wg >= 128);
  const int lwg  = isL1 ? wg - 128 : wg;
  const int j0   = lwg * 4;
  const int kin4 = isL1 ? 128 : 64;
  const int TOT4 = kin4 + 128;
  const float* Wih = isL1 ? Wih1 : Wih0;
  const float* Whh = isL1 ? Whh1 : Whh0;

  // ---- stage 12 gate-rows (gate-major lg=g*4+u) into LDS, K-concatenated ----
  for (int idx = tid; idx < 12*TOT4; idx += TPB){
    int lg = idx / TOT4, k = idx - lg*TOT4;
    int g = lg >> 2, u = lg & 3;
    int row = g*HID + j0 + u;
    float4 v;
    if (k < kin4) v = ((const float4*)Wih)[(size_t)row*kin4 + k];
    else          v = ((const float4*)Whh)[(size_t)row*128 + (k - kin4)];
    smem[lg*TOT4 + k] = v;
  }
  __syncthreads();

  const float* bih = isL1 ? bih1 : bih0;
  const float* bhh = isL1 ? bhh1 : bhh0;
  const int j = j0 + wave;
  const float br  = bih[j]        + bhh[j];
  const float bz  = bih[j + 512]  + bhh[j + 512];
  const float bnx = bih[j + 1024];
  const float bnh = bhh[j + 1024];

  const long lbase = isL1 ? SYNC1 : SYNC0;
  float4* hSelf = (float4*)(ws + (isL1 ? H1F_OFF : H0F_OFF));
  const float4* hIn = (const float4*)(ws + H0F_OFF);
  const float4* xe4 = (const float4*)(ws + XEF_OFF);

  const int KI4W = kin4 >> 2;                 // input f4 per wave (16 / 32)
  const int ik0 = wave * KI4W;
  const int hk0 = wave * 32;                  // hidden f4 per wave = 32

  float hp = 0.f;                             // own h_{t-1}[unit=wave][b=lane]

  for (int t = 0; t < S_LEN; ++t){
    v2f a[16];
    #pragma unroll
    for (int i = 0; i < 16; ++i) a[i] = (v2f)0.0f;

    // ---- input part (overlaps own-chain signal propagation) ----
    if (isL1){
      if (tid == 0)
        wait_flag(ws + SYNC0 + FLAG_OFF + ((long)t*8 + (lwg & 7))*128, 8);
      __syncthreads();
      accum_span(hIn + (long)t*8192, smem, TOT4, ik0, KI4W, lane, 2, a);
    } else if (use_xe){
      accum_span(xe4 + (long)t*4096, smem, TOT4, ik0, KI4W, lane, 2, a);
    } else {
      int tok = x[lane * S_LEN + t];
      const float4* er = (const float4*)emb + (size_t)tok * 64;
      float m = (tok != 0) ? 1.f : 0.f;
      for (int k = ik0; k < ik0 + KI4W; ++k){
        float4 xv = er[k];
        v2f xlo = {xv.x*m, xv.y*m}, xhi = {xv.z*m, xv.w*m};
        #pragma unroll
        for (int g = 0; g < 3; ++g){
          const int cc = (g == 2) ? 2 : g;
          #pragma unroll
          for (int u = 0; u < 4; ++u){
            float4 wv = smem[(g*4 + u)*TOT4 + k];
            v2f wlo = {wv.x, wv.y}, whi = {wv.z, wv.w};
            a[u*4 + cc] = fma2(xlo, wlo, a[u*4 + cc]);
            a[u*4 + cc] = fma2(xhi, whi, a[u*4 + cc]);
          }
        }
      }
    }

    // ---- own-chain wait + hidden part ----
    if (t > 0){
      if (tid == 0)
        wait_flag(ws + lbase + FLAG_OFF + ((long)(t-1)*8 + (lwg & 7))*128, 8);
      __syncthreads();
      const float4* hp4 = hSelf + (long)(t-1)*8192;
      accum_span(hp4, smem + kin4, TOT4, hk0, 32, lane, 3, a);
    }

    // ---- cross-wave reduce: horizontal-sum then LDS partials ----
    #pragma unroll
    for (int i = 0; i < 16; ++i)
      ps[(wave*16 + i)*64 + lane] = a[i].x + a[i].y;
    __syncthreads();

    // ---- gate math: wave == unit ----
    float s0 = 0.f, s1 = 0.f, s2 = 0.f, s3 = 0.f;
    #pragma unroll
    for (int w = 0; w < 4; ++w){
      s0 += ps[(w*16 + wave*4 + 0)*64 + lane];
      s1 += ps[(w*16 + wave*4 + 1)*64 + lane];
      s2 += ps[(w*16 + wave*4 + 2)*64 + lane];
      s3 += ps[(w*16 + wave*4 + 3)*64 + lane];
    }
    float r  = sigmoid_f(s0 + br);
    float zz = sigmoid_f(s1 + bz);
    float n  = tanhf((s2 + bnx) + r * (s3 + bnh));
    float hn = n + zz * (hp - n);
    hp = hn;
    __syncthreads();                          // all partial reads done (htr overlays ps)
    htr[wave*64 + lane] = hn;
    __syncthreads();
    if (wave == 0){
      v4f hv = { htr[lane], htr[64 + lane], htr[128 + lane], htr[192 + lane] };
      store_f4_coh(hSelf + (long)t*8192 + lwg*64 + lane, hv);
    }
    if (tid == 0) signal2(ws, lbase, t, lwg);
  }

  // ---- epilogue: out[b] = sigmoid(h1_511 . Wfc + bfc) ----
  if (wg == 128){
    if (tid == 0)
      wait_flag(ws + SYNC1 + FLAG_OFF + (511L*8 + 0)*128, 8);
    __syncthreads();
    if (wave == 0){
      float acc = bfc[0];
      const float4* h1 = (const float4*)(ws + H1F_OFF + 511L*SLOT);
      const float4* wf = (const float4*)Wfc;
      #pragma unroll 4
      for (int k = 0; k < 128; ++k){
        float4 hv = h1[k*64 + lane];
        float4 wv = wf[k];
        acc = fmaf(hv.x, wv.x, acc); acc = fmaf(hv.y, wv.y, acc);
        acc = fmaf(hv.z, wv.z, acc); acc = fmaf(hv.w, wv.w, acc);
      }
      out[lane] = sigmoid_f(acc);
    }
  }
}

// =====================================================================
// FALLBACK (fence-based) — only when ws too small for the fast path.
// =====================================================================
__device__ __forceinline__ void accum_vec(const float4* __restrict__ xin,
                                          const float4* __restrict__ w0,
                                          const float4* __restrict__ w1,
                                          const float4* __restrict__ w2,
                                          int n4, int lane,
                                          float& ar, float& az, float& an)
{
  #pragma unroll 4
  for (int k = 0; k < n4; ++k){
    float4 xv = xin[k * 64 + lane];
    float4 wr = w0[k], wz = w1[k], wn = w2[k];
    ar = fmaf(xv.x, wr.x, ar); az = fmaf(xv.x, wz.x, az); an = fmaf(xv.x, wn.x, an);
    ar = fmaf(xv.y, wr.y, ar); az = fmaf(xv.y, wz.y, az); an = fmaf(xv.y, wn.y, an);
    ar = fmaf(xv.z, wr.z, ar); az = fmaf(xv.z, wz.z, az); an = fmaf(xv.z, wn.z, an);
    ar = fmaf(xv.w, wr.w, ar); az = fmaf(xv.w, wz.w, az); an = fmaf(xv.w, wn.w, an);
  }
}

__device__ __forceinline__ void accum_emb(const int* __restrict__ x,
                                          const float* __restrict__ emb, int t,
                                          const float4* __restrict__ w0,
                                          const float4* __restrict__ w1,
                                          const float4* __restrict__ w2,
                                          int lane, float& ar, float& az, float& an)
{
  int tok = x[lane * S_LEN + t];
  const float4* erow = (const float4*)emb + (size_t)tok * 64;
  float m = (tok != 0) ? 1.0f : 0.0f;
  #pragma unroll 4
  for (int k = 0; k < 64; ++k){
    float4 xv = erow[k];
    float xx = xv.x*m, xy = xv.y*m, xz = xv.z*m, xw = xv.w*m;
    float4 wr = w0[k], wz = w1[k], wn = w2[k];
    ar = fmaf(xx, wr.x, ar); az = fmaf(xx, wz.x, az); an = fmaf(xx, wn.x, an);
    ar = fmaf(xy, wr.y, ar); az = fmaf(xy, wz.y, az); an = fmaf(xy, wn.y, an);
    ar = fmaf(xz, wr.z, ar); az = fmaf(xz, wz.z, az); an = fmaf(xz, wn.z, an);
    ar = fmaf(xw, wr.w, ar); az = fmaf(xw, wz.w, az); an = fmaf(xw, wn.w, an);
  }
}

__device__ __forceinline__ void stage_weights(float4* wlds, int tid, int j0, int kin4,
                                              const float* Wih, const float* Whh)
{
  const int per = 3 * (kin4 + 128);
  for (int idx = tid; idx < 4 * per; idx += TPB){
    int w = idx / per, rem = idx - w * per;
    int g = rem / (kin4 + 128), k = rem - g * (kin4 + 128);
    int row = g * HID + j0 + w;
    float4 v;
    if (k < kin4) v = ((const float4*)Wih)[(size_t)row * kin4 + k];
    else          v = ((const float4*)Whh)[(size_t)row * 128 + (k - kin4)];
    wlds[(w * 3 + g) * 256 + k] = v;
  }
}

__device__ __forceinline__ void barrier_tick(int* bar, int wg, int tid, int phase)
{
  __syncthreads();
  if (tid == 0){
    __builtin_amdgcn_fence(__ATOMIC_RELEASE, "agent");
    int* leaf = bar + 32 + (wg >> 4) * 32;
    int old = __hip_atomic_fetch_add(leaf, 1, __ATOMIC_ACQ_REL, __HIP_MEMORY_SCOPE_AGENT);
    if (old == phase * 16 + 15){
      __hip_atomic_fetch_add(bar, 1, __ATOMIC_ACQ_REL, __HIP_MEMORY_SCOPE_AGENT);
    }
    const int target = (phase + 1) * 16;
    while (__hip_atomic_load(bar, __ATOMIC_ACQUIRE, __HIP_MEMORY_SCOPE_AGENT) < target){
      __builtin_amdgcn_s_sleep(2);
    }
    __builtin_amdgcn_fence(__ATOMIC_ACQUIRE, "agent");
  }
  __syncthreads();
}

__device__ __forceinline__ void finish_store(const float4* __restrict__ hprev,
                                             float ar, float az, float anx, float anh,
                                             int lane, int j, float4* __restrict__ hout)
{
  float r  = sigmoid_f(ar);
  float zz = sigmoid_f(az);
  float n  = tanhf(fmaf(r, anh, anx));
  int fi = ((j >> 2) * 64 + lane) * 4 + (j & 3);
  float hhp = ((const float*)hprev)[fi];
  ((float*)hout)[fi] = fmaf(zz, hhp - n, n);
}

__global__ __launch_bounds__(TPB) void gru_persist_kernel(
    const int*   __restrict__ x,    const float* __restrict__ emb,
    const float* __restrict__ Wih0, const float* __restrict__ Whh0,
    const float* __restrict__ bih0, const float* __restrict__ bhh0,
    const float* __restrict__ Wih1, const float* __restrict__ Whh1,
    const float* __restrict__ bih1, const float* __restrict__ bhh1,
    const float* __restrict__ Wfc,  const float* __restrict__ bfc,
    float* __restrict__ out, int* __restrict__ bar,
    float4* __restrict__ A0, float4* __restrict__ A1,
    float4* __restrict__ B0, float4* __restrict__ B1,
    const float4* __restrict__ xe4, int use_xe)
{
  __shared__ float4 wlds[3072];
  const int tid  = threadIdx.x;
  const int wg   = blockIdx.x;
  const int lane = tid & 63;
  const int wave = tid >> 6;
  const bool isL1 = (wg >= 128);
  const int j0   = (isL1 ? wg - 128 : wg) * 4;
  const int kin4 = isL1 ? 128 : 64;

  stage_weights(wlds, tid, j0, kin4, isL1 ? Wih1 : Wih0, isL1 ? Whh1 : Whh0);
  __syncthreads();

  const int j = j0 + wave;
  const float* bih = isL1 ? bih1 : bih0;
  const float* bhh = isL1 ? bhh1 : bhh0;
  const float br  = bih[j]        + bhh[j];
  const float bz  = bih[j + 512]  + bhh[j + 512];
  const float bnx = bih[j + 1024];
  const float bnh = bhh[j + 1024];

  const float4* w0 = &wlds[(wave * 3 + 0) * 256];
  const float4* w1 = &wlds[(wave * 3 + 1) * 256];
  const float4* w2 = &wlds[(wave * 3 + 2) * 256];

  float4* A[2] = {A0, A1};
  float4* B[2] = {B0, B1};

  for (int t = 0; t <= S_LEN; ++t){
    if (!isL1){
      if (t < S_LEN){
        const float4* hprev = A[(t + 1) & 1];
        float ar = br, az = bz, anx = bnx, anh = bnh;
        if (use_xe) accum_vec(xe4 + (size_t)t * 4096, w0, w1, w2, 64, lane, ar, az, anx);
        else        accum_emb(x, emb, t, w0, w1, w2, lane, ar, az, anx);
        accum_vec(hprev, w0 + 64, w1 + 64, w2 + 64, 128, lane, ar, az, anh);
        finish_store(hprev, ar, az, anx, anh, lane, j, A[t & 1]);
      }
    } else if (t >= 1){
      const int u = t - 1;
      const float4* xin   = A[u & 1];
      const float4* hprev = B[(u + 1) & 1];
      float ar = br, az = bz, anx = bnx, anh = bnh;
      accum_vec(xin,   w0,       w1,       w2,       128, lane, ar, az, anx);
      accum_vec(hprev, w0 + 128, w1 + 128, w2 + 128, 128, lane, ar, az, anh);
      finish_store(hprev, ar, az, anx, anh, lane, j, B[u & 1]);
    }
    barrier_tick(bar, wg, tid, t);
  }

  if (wg == 0 && wave == 0){
    float acc = bfc[0];
    const float4* h1 = B[1];
    const float4* wf = (const float4*)Wfc;
    #pragma unroll 4
    for (int k = 0; k < 128; ++k){
      float4 hv = h1[k * 64 + lane];
      float4 wv = wf[k];
      acc = fmaf(hv.x, wv.x, acc); acc = fmaf(hv.y, wv.y, acc);
      acc = fmaf(hv.z, wv.z, acc); acc = fmaf(hv.w, wv.w, acc);
    }
    out[lane] = sigmoid_f(acc);
  }
}

extern "C" void kernel_launch(void* const* d_in, const int* in_sizes, int n_in,
                              void* d_out, int out_size, void* d_ws, size_t ws_size,
                              hipStream_t stream)
{
  (void)in_sizes; (void)n_in; (void)out_size;
  const int*   x    = (const int*)  d_in[0];
  const float* emb  = (const float*)d_in[1];
  const float* Wih0 = (const float*)d_in[2];
  const float* Whh0 = (const float*)d_in[3];
  const float* bih0 = (const float*)d_in[4];
  const float* bhh0 = (const float*)d_in[5];
  const float* Wih1 = (const float*)d_in[6];
  const float* Whh1 = (const float*)d_in[7];
  const float* bih1 = (const float*)d_in[8];
  const float* bhh1 = (const float*)d_in[9];
  const float* Wfc  = (const float*)d_in[10];
  const float* bfc  = (const float*)d_in[11];
  float* out = (float*)d_out;
  char* ws = (char*)d_ws;

  if (ws_size >= (size_t)FAST_MIN){
    const int use_xe = (ws_size >= (size_t)FAST_XE) ? 1 : 0;
    hipMemsetAsync(ws, 0, (size_t)(2L<<20), stream);     // zero sync counters
    if (use_xe){
      gather_xe_kernel<<<(S_LEN * 64 * BATCH) / TPB, TPB, 0, stream>>>(
          x, emb, (float4*)(ws + XEF_OFF));
    }
    gru_fast2_kernel<<<NWG, TPB, 0, stream>>>(
        x, emb, Wih0, Whh0, bih0, bhh0, Wih1, Whh1, bih1, bhh1, Wfc, bfc,
        out, ws, use_xe);
  } else {
    int*    bar = (int*)ws;
    float4* A0  = (float4*)(ws + A_OFF);
    float4* A1  = (float4*)(ws + A_OFF + HBUF_BYTES);
    float4* B0  = (float4*)(ws + B_OFF);
    float4* B1  = (float4*)(ws + B_OFF + HBUF_BYTES);
    float4* xe4 = (float4*)(ws + XE_OFF);
    const int use_xe = (ws_size >= (size_t)XE_OFF + XE_BYTES) ? 1 : 0;
    hipMemsetAsync(ws, 0, XE_OFF, stream);
    if (use_xe){
      gather_xe_kernel<<<(S_LEN * 64 * BATCH) / TPB, TPB, 0, stream>>>(x, emb, xe4);
    }
    gru_persist_kernel<<<NWG, TPB, 0, stream>>>(
        x, emb, Wih0, Whh0, bih0, bhh0, Wih1, Whh1, bih1, bhh1, Wfc, bfc,
        out, bar, A0, A1, B0, B1, xe4, use_xe);
  }
}

// Round 4
// 2720.358 us; speedup vs baseline: 11.8980x; 2.9228x over previous
//
#include <hip/hip_runtime.h>
#include <math.h>

typedef short  s8v __attribute__((ext_vector_type(8)));   // 8 bf16 (4 VGPRs)
typedef float  f4v __attribute__((ext_vector_type(4)));
typedef float  v2f __attribute__((ext_vector_type(2)));
typedef unsigned int u2v __attribute__((ext_vector_type(2)));

#define S_LEN 512
#define BATCH 64
#define HID   512
#define TPB   256

// ---------------- fast-path workspace layout ----------------
#define SYNCF_BYTES 3145728L                 // [l][m][t][12 lines]*128B
#define WI0H_OFF 3145728L
#define WI0L_OFF (WI0H_OFF + 786432L)
#define WH0H_OFF (WI0L_OFF + 786432L)
#define WH0L_OFF (WH0H_OFF + 1572864L)
#define WI1H_OFF (WH0L_OFF + 1572864L)
#define WI1L_OFF (WI1H_OFF + 1572864L)
#define WH1H_OFF (WI1L_OFF + 1572864L)
#define WH1L_OFF (WH1H_OFF + 1572864L)
#define XEB_OFF  (WH1L_OFF + 1572864L)       // 14,155,776: xe bf16 [t*64+b][256]
#define H0B_OFF  (XEB_OFF + 16777216L)       // 30,932,992: h0 bf16 [t][b][512]
#define H1B_OFF  (H0B_OFF + 33554432L)       // 64,487,424
#define NEED_FAST (H1B_OFF + 33554432L)      // 98,041,856

// ---------------- fallback (fence path, R1) layout ----------------
#define BAR_BYTES   4096
#define HBUF_BYTES  (HID*BATCH*4)
#define A_OFF       BAR_BYTES
#define B_OFF       (A_OFF + 2*HBUF_BYTES)
#define XE_OFF      (B_OFF + 2*HBUF_BYTES)
#define XE_BYTES    ((size_t)S_LEN*64*BATCH*16)

__device__ __forceinline__ float fexp2(float x){ return __builtin_amdgcn_exp2f(x); }
__device__ __forceinline__ float frcp (float x){ return __builtin_amdgcn_rcpf(x); }
__device__ __forceinline__ float sigm (float x){ return frcp(1.f + fexp2(-1.44269504089f*x)); }
__device__ __forceinline__ float tanhx(float x){ return 1.f - 2.f*frcp(1.f + fexp2(2.88539008178f*x)); }
__device__ __forceinline__ float sigmoid_f(float v){ return 1.0f/(1.0f + expf(-v)); }

__device__ __forceinline__ unsigned short f2bf(float f){
  unsigned int u = __float_as_uint(f);
  u = u + 0x7FFFu + ((u >> 16) & 1u);          // RNE
  return (unsigned short)(u >> 16);
}
__device__ __forceinline__ float bf2f(unsigned short s){
  return __uint_as_float(((unsigned int)s) << 16);
}

// =====================================================================
// Phase A kernels
// =====================================================================
// split 4 weight matrices into bf16 hi/lo row-major buffers
__global__ void wcvt_kernel(const float* __restrict__ Wih0, const float* __restrict__ Whh0,
                            const float* __restrict__ Wih1, const float* __restrict__ Whh1,
                            char* __restrict__ ws)
{
  int idx = blockIdx.x * TPB + threadIdx.x;    // 2,752,512 total
  const float* src; long hi_off, lo_off; int pos;
  if (idx < 393216)       { src = Wih0; pos = idx;           hi_off = WI0H_OFF; lo_off = WI0L_OFF; }
  else if (idx < 1179648) { src = Whh0; pos = idx - 393216;  hi_off = WH0H_OFF; lo_off = WH0L_OFF; }
  else if (idx < 1966080) { src = Wih1; pos = idx - 1179648; hi_off = WI1H_OFF; lo_off = WI1L_OFF; }
  else                    { src = Whh1; pos = idx - 1966080; hi_off = WH1H_OFF; lo_off = WH1L_OFF; }
  float w = src[pos];
  unsigned short h = f2bf(w);
  unsigned short l = f2bf(w - bf2f(h));
  ((unsigned short*)(ws + hi_off))[pos] = h;
  ((unsigned short*)(ws + lo_off))[pos] = l;
}

// gather embeddings -> xe_bf[n = t*64+b][k 0..255] bf16 (pad row zero)
__global__ void gather_xe_bf_kernel(const int* __restrict__ x,
                                    const float* __restrict__ emb,
                                    char* __restrict__ ws)
{
  int idx = blockIdx.x * TPB + threadIdx.x;    // 2,097,152 = 32768 n * 64 k4
  int k4 = idx & 63;
  int n  = idx >> 6;
  int t = n >> 6, b = n & 63;
  int tok = x[b * S_LEN + t];
  float4 v = make_float4(0.f,0.f,0.f,0.f);
  if (tok != 0) v = ((const float4*)emb)[(size_t)tok * 64 + k4];
  unsigned int lo = (unsigned int)f2bf(v.x) | ((unsigned int)f2bf(v.y) << 16);
  unsigned int hi = (unsigned int)f2bf(v.z) | ((unsigned int)f2bf(v.w) << 16);
  ((uint2*)(ws + XEB_OFF))[(long)n * 64 + k4] = make_uint2(lo, hi);
}

// =====================================================================
// sync primitives (relaxed agent atomics; no cache-maintenance fences)
// line layout per (l,m,t): lines 0..3 = leaf (8 WGs each), 4..11 = flag replicas
// =====================================================================
__device__ __forceinline__ int* sync_line(char* ws, int l, int m, int t, int line){
  return (int*)(ws + (((((long)l*2 + m)*512 + t)*12 + line) << 7));
}
__device__ __forceinline__ void wave_wait(int* p, int target){
  while (__hip_atomic_load(p, __ATOMIC_RELAXED, __HIP_MEMORY_SCOPE_AGENT) < target)
    __builtin_amdgcn_s_sleep(2);
}
__device__ __forceinline__ void signal_tick(char* ws, int l, int m, int t, int rowWG){
  int old = __hip_atomic_fetch_add(sync_line(ws, l, m, t, rowWG >> 3), 1,
                                   __ATOMIC_RELAXED, __HIP_MEMORY_SCOPE_AGENT);
  if (old == 7){
    #pragma unroll
    for (int c = 0; c < 8; ++c)
      __hip_atomic_fetch_add(sync_line(ws, l, m, t, 4 + c), 1,
                             __ATOMIC_RELAXED, __HIP_MEMORY_SCOPE_AGENT);
  }
}
__device__ __forceinline__ void store_b8_coh(void* p, u2v v){
  asm volatile("global_store_dwordx2 %0, %1, off sc0 sc1" :: "v"(p), "v"(v) : "memory");
}

// =====================================================================
// scan body: one wave's role for the whole 512-tick loop.
// SRCMODE: 0 = xe input (no poll), 1 = self-layer h (poll own t-1, slot t-1),
//          2 = cross h0 (poll L0 flag t, slot t)
// Each tick: MFMA partials (K-slice) -> LDS reduce -> gate math (lane<32) ->
// bf16 h store (write-through) -> signal.
// =====================================================================
template<int NKS, int SRCMODE>
__device__ __forceinline__ void scan_body(
    int isL1, int rowWG, int bh, int wave, int lane, int tid, int j0, int b0,
    const s8v* __restrict__ Whi, const s8v* __restrict__ Wlo, int AKs, int k0s,
    const s8v* __restrict__ bsrc, int srcKs,
    const float* __restrict__ bih, const float* __restrict__ bhh,
    char* __restrict__ ws, unsigned short* __restrict__ hout,
    f4v* __restrict__ part)
{
  const int quad = lane >> 4, col = lane & 15;

  // ---- A fragments in registers for all 512 ticks (hi + lo) ----
  s8v ahi[3][NKS], alo[3][NKS];
  #pragma unroll
  for (int rt = 0; rt < 3; ++rt){
    const int row = rt*512 + j0 + col;
    #pragma unroll
    for (int ks = 0; ks < NKS; ++ks){
      const int e = row*AKs + k0s + ks*4 + quad;
      ahi[rt][ks] = Whi[e];
      alo[rt][ks] = Wlo[e];
    }
  }

  // ---- per-thread gate constants + persistent fp32 h (lane<32) ----
  float cr[4], cz[4], cnx[4], cnh[4], hp[4];
  #pragma unroll
  for (int r4 = 0; r4 < 4; ++r4){
    int j = j0 + wave*4 + r4;
    cr[r4]  = bih[j]      + bhh[j];
    cz[r4]  = bih[512+j]  + bhh[512+j];
    cnx[r4] = bih[1024+j];
    cnh[r4] = bhh[1024+j];
    hp[r4]  = 0.f;
  }

  const int pollLayer = (SRCMODE == 2) ? 0 : isL1;
  const int rep = rowWG & 7;

  for (int t = 0; t < S_LEN; ++t){
    if (SRCMODE == 1){ if (t > 0) wave_wait(sync_line(ws, pollLayer, bh, t-1, 4+rep), 4); }
    else if (SRCMODE == 2){        wave_wait(sync_line(ws, pollLayer, bh, t,   4+rep), 4); }

    f4v acc[3][2];
    #pragma unroll
    for (int rt = 0; rt < 3; ++rt){ acc[rt][0] = (f4v)0.f; acc[rt][1] = (f4v)0.f; }

    const bool active = (SRCMODE != 1) || (t > 0);
    if (active){
      const int slot = (SRCMODE == 1) ? (t-1) : t;
      #pragma unroll
      for (int ct = 0; ct < 2; ++ct){
        const int nG = b0 + ct*16 + col;
        const long base = ((long)slot*64 + nG)*srcKs + k0s + quad;
        s8v bf[NKS];
        #pragma unroll
        for (int ks = 0; ks < NKS; ++ks) bf[ks] = bsrc[base + ks*4];
        #pragma unroll
        for (int ks = 0; ks < NKS; ++ks){
          #pragma unroll
          for (int rt = 0; rt < 3; ++rt){
            acc[rt][ct] = __builtin_amdgcn_mfma_f32_16x16x32_bf16(ahi[rt][ks], bf[ks], acc[rt][ct], 0, 0, 0);
            acc[rt][ct] = __builtin_amdgcn_mfma_f32_16x16x32_bf16(alo[rt][ks], bf[ks], acc[rt][ct], 0, 0, 0);
          }
        }
      }
    }

    // ---- partials to LDS ----
    #pragma unroll
    for (int rt = 0; rt < 3; ++rt)
      #pragma unroll
      for (int ct = 0; ct < 2; ++ct)
        part[(wave*6 + rt*2 + ct)*64 + lane] = acc[rt][ct];
    __syncthreads();

    // ---- reduce + gate math: thread (wave=unit-group, lane<32 = local b) ----
    if (lane < 32){
      const int b = lane;
      f4v sr = (f4v)0.f, sz = (f4v)0.f, snx = (f4v)0.f, snh = (f4v)0.f;
      #pragma unroll
      for (int w = 0; w < 4; ++w){
        const bool inpW = isL1 ? (w < 2) : (w >= 2);
        const int li = w*6;
        const int le = (b>>4)*64 + wave*16 + (b&15);
        f4v v0 = part[(li + 0)*64 + le - (b>>4)*64 + (b>>4)*64]; // (kept simple below)
        v0 = part[(li + 0 + 0)*64 + 0];                          // placeholder overwritten
        // -- real reads --
        f4v g0 = part[(li + 0*2 + (b>>4))*64 + wave*16 + (b&15)];
        f4v g1 = part[(li + 1*2 + (b>>4))*64 + wave*16 + (b&15)];
        f4v g2 = part[(li + 2*2 + (b>>4))*64 + wave*16 + (b&15)];
        sr += g0; sz += g1;
        if (inpW) snx += g2; else snh += g2;
        (void)v0;
      }
      unsigned short hb[4];
      #pragma unroll
      for (int r4 = 0; r4 < 4; ++r4){
        float r = sigm(sr[r4] + cr[r4]);
        float z = sigm(sz[r4] + cz[r4]);
        float n = tanhx(snx[r4] + cnx[r4] + r*(snh[r4] + cnh[r4]));
        float h = n + z*(hp[r4] - n);
        hp[r4] = h;
        hb[r4] = f2bf(h);
      }
      u2v val;
      val.x = (unsigned int)hb[0] | ((unsigned int)hb[1] << 16);
      val.y = (unsigned int)hb[2] | ((unsigned int)hb[3] << 16);
      unsigned short* dst = hout + (((long)t*64 + b0 + b)*512 + j0 + wave*4);
      store_b8_coh((void*)dst, val);
    }
    asm volatile("s_waitcnt vmcnt(0)" ::: "memory");
    __syncthreads();
    if (tid == 0) signal_tick(ws, isL1, bh, t, rowWG);
  }
}

// =====================================================================
// Persistent MFMA scan kernel: 128 WGs.
// wg 0..63: layer0, wg 64..127: layer1. lw=wg&63: rowWG=lw>>1 (16 units), bh=lw&1 (32 batch).
// =====================================================================
__global__ __launch_bounds__(TPB, 1) void gru_mfma_kernel(
    const float* __restrict__ bih0, const float* __restrict__ bhh0,
    const float* __restrict__ bih1, const float* __restrict__ bhh1,
    const float* __restrict__ Wfc,  const float* __restrict__ bfc,
    float* __restrict__ out, char* __restrict__ ws)
{
  __shared__ f4v part[4*6*64];                 // 24 KB partial-reduce buffer

  const int tid  = threadIdx.x;
  const int wg   = blockIdx.x;
  const int lane = tid & 63;
  const int wave = tid >> 6;
  const int isL1 = (wg >= 64);
  const int lw   = wg & 63;
  const int rowWG = lw >> 1;
  const int bh    = lw & 1;
  const int j0 = rowWG * 16;
  const int b0 = bh * 32;

  const s8v* wi0h = (const s8v*)(ws + WI0H_OFF); const s8v* wi0l = (const s8v*)(ws + WI0L_OFF);
  const s8v* wh0h = (const s8v*)(ws + WH0H_OFF); const s8v* wh0l = (const s8v*)(ws + WH0L_OFF);
  const s8v* wi1h = (const s8v*)(ws + WI1H_OFF); const s8v* wi1l = (const s8v*)(ws + WI1L_OFF);
  const s8v* wh1h = (const s8v*)(ws + WH1H_OFF); const s8v* wh1l = (const s8v*)(ws + WH1L_OFF);
  const s8v* xeb = (const s8v*)(ws + XEB_OFF);
  const s8v* h0b = (const s8v*)(ws + H0B_OFF);
  const s8v* h1b = (const s8v*)(ws + H1B_OFF);
  unsigned short* h0o = (unsigned short*)(ws + H0B_OFF);
  unsigned short* h1o = (unsigned short*)(ws + H1B_OFF);

  if (!isL1){
    if (wave < 2)
      scan_body<8,1>(isL1, rowWG, bh, wave, lane, tid, j0, b0,
                     wh0h, wh0l, 64, wave*32, h0b, 64, bih0, bhh0, ws, h0o, part);
    else
      scan_body<4,0>(isL1, rowWG, bh, wave, lane, tid, j0, b0,
                     wi0h, wi0l, 32, (wave-2)*16, xeb, 32, bih0, bhh0, ws, h0o, part);
  } else {
    if (wave < 2)
      scan_body<8,2>(isL1, rowWG, bh, wave, lane, tid, j0, b0,
                     wi1h, wi1l, 64, wave*32, h0b, 64, bih1, bhh1, ws, h1o, part);
    else
      scan_body<8,1>(isL1, rowWG, bh, wave, lane, tid, j0, b0,
                     wh1h, wh1l, 64, (wave-2)*32, h1b, 64, bih1, bhh1, ws, h1o, part);
  }

  // ---- epilogue FC: out[b] = sigmoid(h1_511 . Wfc + bfc) ----
  if (wg == 64 && wave == 0){
    wave_wait(sync_line(ws, 1, 0, 511, 4+0), 4);
    wave_wait(sync_line(ws, 1, 1, 511, 4+1), 4);
    float acc = bfc[0];
    const s8v* h1v = h1b + ((long)511*64 + lane)*64;
    const float4* wf = (const float4*)Wfc;
    #pragma unroll 4
    for (int kk = 0; kk < 64; ++kk){
      s8v hv = h1v[kk];
      float4 w0 = wf[kk*2], w1 = wf[kk*2+1];
      acc += bf2f((unsigned short)hv[0])*w0.x + bf2f((unsigned short)hv[1])*w0.y
           + bf2f((unsigned short)hv[2])*w0.z + bf2f((unsigned short)hv[3])*w0.w
           + bf2f((unsigned short)hv[4])*w1.x + bf2f((unsigned short)hv[5])*w1.y
           + bf2f((unsigned short)hv[6])*w1.z + bf2f((unsigned short)hv[7])*w1.w;
    }
    out[lane] = sigm(acc);
  }
}

// =====================================================================
// FALLBACK (R1 fence path) — only if ws too small for the fast path.
// =====================================================================
__global__ void gather_xe_kernel(const int* __restrict__ x,
                                 const float* __restrict__ emb,
                                 float4* __restrict__ xe4)
{
  int idx = blockIdx.x * TPB + threadIdx.x;
  int b  = idx & 63;
  int k4 = (idx >> 6) & 63;
  int t  = idx >> 12;
  int tok = x[b * S_LEN + t];
  float4 v = make_float4(0.f, 0.f, 0.f, 0.f);
  if (tok != 0) v = ((const float4*)emb)[(size_t)tok * 64 + k4];
  xe4[idx] = v;
}

__device__ __forceinline__ void accum_vec(const float4* __restrict__ xin,
                                          const float4* __restrict__ w0,
                                          const float4* __restrict__ w1,
                                          const float4* __restrict__ w2,
                                          int n4, int lane,
                                          float& ar, float& az, float& an)
{
  #pragma unroll 4
  for (int k = 0; k < n4; ++k){
    float4 xv = xin[k * 64 + lane];
    float4 wr = w0[k], wz = w1[k], wn = w2[k];
    ar = fmaf(xv.x, wr.x, ar); az = fmaf(xv.x, wz.x, az); an = fmaf(xv.x, wn.x, an);
    ar = fmaf(xv.y, wr.y, ar); az = fmaf(xv.y, wz.y, az); an = fmaf(xv.y, wn.y, an);
    ar = fmaf(xv.z, wr.z, ar); az = fmaf(xv.z, wz.z, az); an = fmaf(xv.z, wn.z, an);
    ar = fmaf(xv.w, wr.w, ar); az = fmaf(xv.w, wz.w, az); an = fmaf(xv.w, wn.w, an);
  }
}

__device__ __forceinline__ void accum_emb(const int* __restrict__ x,
                                          const float* __restrict__ emb, int t,
                                          const float4* __restrict__ w0,
                                          const float4* __restrict__ w1,
                                          const float4* __restrict__ w2,
                                          int lane, float& ar, float& az, float& an)
{
  int tok = x[lane * S_LEN + t];
  const float4* erow = (const float4*)emb + (size_t)tok * 64;
  float m = (tok != 0) ? 1.0f : 0.0f;
  #pragma unroll 4
  for (int k = 0; k < 64; ++k){
    float4 xv = erow[k];
    float xx = xv.x*m, xy = xv.y*m, xz = xv.z*m, xw = xv.w*m;
    float4 wr = w0[k], wz = w1[k], wn = w2[k];
    ar = fmaf(xx, wr.x, ar); az = fmaf(xx, wz.x, az); an = fmaf(xx, wn.x, an);
    ar = fmaf(xy, wr.y, ar); az = fmaf(xy, wz.y, az); an = fmaf(xy, wn.y, an);
    ar = fmaf(xz, wr.z, ar); az = fmaf(xz, wz.z, az); an = fmaf(xz, wn.z, an);
    ar = fmaf(xw, wr.w, ar); az = fmaf(xw, wz.w, az); an = fmaf(xw, wn.w, an);
  }
}

__device__ __forceinline__ void stage_weights(float4* wlds, int tid, int j0, int kin4,
                                              const float* Wih, const float* Whh)
{
  const int per = 3 * (kin4 + 128);
  for (int idx = tid; idx < 4 * per; idx += TPB){
    int w = idx / per, rem = idx - w * per;
    int g = rem / (kin4 + 128), k = rem - g * (kin4 + 128);
    int row = g * HID + j0 + w;
    float4 v;
    if (k < kin4) v = ((const float4*)Wih)[(size_t)row * kin4 + k];
    else          v = ((const float4*)Whh)[(size_t)row * 128 + (k - kin4)];
    wlds[(w * 3 + g) * 256 + k] = v;
  }
}

__device__ __forceinline__ void barrier_tick(int* bar, int wg, int tid, int phase)
{
  __syncthreads();
  if (tid == 0){
    __builtin_amdgcn_fence(__ATOMIC_RELEASE, "agent");
    int* leaf = bar + 32 + (wg >> 4) * 32;
    int old = __hip_atomic_fetch_add(leaf, 1, __ATOMIC_ACQ_REL, __HIP_MEMORY_SCOPE_AGENT);
    if (old == phase * 16 + 15){
      __hip_atomic_fetch_add(bar, 1, __ATOMIC_ACQ_REL, __HIP_MEMORY_SCOPE_AGENT);
    }
    const int target = (phase + 1) * 16;
    while (__hip_atomic_load(bar, __ATOMIC_ACQUIRE, __HIP_MEMORY_SCOPE_AGENT) < target){
      __builtin_amdgcn_s_sleep(2);
    }
    __builtin_amdgcn_fence(__ATOMIC_ACQUIRE, "agent");
  }
  __syncthreads();
}

__device__ __forceinline__ void finish_store(const float4* __restrict__ hprev,
                                             float ar, float az, float anx, float anh,
                                             int lane, int j, float4* __restrict__ hout)
{
  float r  = sigmoid_f(ar);
  float zz = sigmoid_f(az);
  float n  = tanhf(fmaf(r, anh, anx));
  int fi = ((j >> 2) * 64 + lane) * 4 + (j & 3);
  float hhp = ((const float*)hprev)[fi];
  ((float*)hout)[fi] = fmaf(zz, hhp - n, n);
}

__global__ __launch_bounds__(TPB) void gru_persist_kernel(
    const int*   __restrict__ x,    const float* __restrict__ emb,
    const float* __restrict__ Wih0, const float* __restrict__ Whh0,
    const float* __restrict__ bih0, const float* __restrict__ bhh0,
    const float* __restrict__ Wih1, const float* __restrict__ Whh1,
    const float* __restrict__ bih1, const float* __restrict__ bhh1,
    const float* __restrict__ Wfc,  const float* __restrict__ bfc,
    float* __restrict__ out, int* __restrict__ bar,
    float4* __restrict__ A0, float4* __restrict__ A1,
    float4* __restrict__ B0, float4* __restrict__ B1,
    const float4* __restrict__ xe4, int use_xe)
{
  __shared__ float4 wlds[3072];
  const int tid  = threadIdx.x;
  const int wg   = blockIdx.x;
  const int lane = tid & 63;
  const int wave = tid >> 6;
  const bool isL1 = (wg >= 128);
  const int j0   = (isL1 ? wg - 128 : wg) * 4;
  const int kin4 = isL1 ? 128 : 64;

  stage_weights(wlds, tid, j0, kin4, isL1 ? Wih1 : Wih0, isL1 ? Whh1 : Whh0);
  __syncthreads();

  const int j = j0 + wave;
  const float* bih = isL1 ? bih1 : bih0;
  const float* bhh = isL1 ? bhh1 : bhh0;
  const float br  = bih[j]        + bhh[j];
  const float bz  = bih[j + 512]  + bhh[j + 512];
  const float bnx = bih[j + 1024];
  const float bnh = bhh[j + 1024];

  const float4* w0 = &wlds[(wave * 3 + 0) * 256];
  const float4* w1 = &wlds[(wave * 3 + 1) * 256];
  const float4* w2 = &wlds[(wave * 3 + 2) * 256];

  float4* A[2] = {A0, A1};
  float4* B[2] = {B0, B1};

  for (int t = 0; t <= S_LEN; ++t){
    if (!isL1){
      if (t < S_LEN){
        const float4* hprev = A[(t + 1) & 1];
        float ar = br, az = bz, anx = bnx, anh = bnh;
        if (use_xe) accum_vec(xe4 + (size_t)t * 4096, w0, w1, w2, 64, lane, ar, az, anx);
        else        accum_emb(x, emb, t, w0, w1, w2, lane, ar, az, anx);
        accum_vec(hprev, w0 + 64, w1 + 64, w2 + 64, 128, lane, ar, az, anh);
        finish_store(hprev, ar, az, anx, anh, lane, j, A[t & 1]);
      }
    } else if (t >= 1){
      const int u = t - 1;
      const float4* xin   = A[u & 1];
      const float4* hprev = B[(u + 1) & 1];
      float ar = br, az = bz, anx = bnx, anh = bnh;
      accum_vec(xin,   w0,       w1,       w2,       128, lane, ar, az, anx);
      accum_vec(hprev, w0 + 128, w1 + 128, w2 + 128, 128, lane, ar, az, anh);
      finish_store(hprev, ar, az, anx, anh, lane, j, B[u & 1]);
    }
    barrier_tick(bar, wg, tid, t);
  }

  if (wg == 0 && wave == 0){
    float acc = bfc[0];
    const float4* h1 = B[1];
    const float4* wf = (const float4*)Wfc;
    #pragma unroll 4
    for (int k = 0; k < 128; ++k){
      float4 hv = h1[k * 64 + lane];
      float4 wv = wf[k];
      acc = fmaf(hv.x, wv.x, acc); acc = fmaf(hv.y, wv.y, acc);
      acc = fmaf(hv.z, wv.z, acc); acc = fmaf(hv.w, wv.w, acc);
    }
    out[lane] = sigmoid_f(acc);
  }
}

extern "C" void kernel_launch(void* const* d_in, const int* in_sizes, int n_in,
                              void* d_out, int out_size, void* d_ws, size_t ws_size,
                              hipStream_t stream)
{
  (void)in_sizes; (void)n_in; (void)out_size;
  const int*   x    = (const int*)  d_in[0];
  const float* emb  = (const float*)d_in[1];
  const float* Wih0 = (const float*)d_in[2];
  const float* Whh0 = (const float*)d_in[3];
  const float* bih0 = (const float*)d_in[4];
  const float* bhh0 = (const float*)d_in[5];
  const float* Wih1 = (const float*)d_in[6];
  const float* Whh1 = (const float*)d_in[7];
  const float* bih1 = (const float*)d_in[8];
  const float* bhh1 = (const float*)d_in[9];
  const float* Wfc  = (const float*)d_in[10];
  const float* bfc  = (const float*)d_in[11];
  float* out = (float*)d_out;
  char* ws = (char*)d_ws;

  if (ws_size >= (size_t)NEED_FAST){
    hipMemsetAsync(ws, 0, (size_t)SYNCF_BYTES, stream);                 // sync counters
    wcvt_kernel<<<2752512 / TPB, TPB, 0, stream>>>(Wih0, Whh0, Wih1, Whh1, ws);
    gather_xe_bf_kernel<<<2097152 / TPB, TPB, 0, stream>>>(x, emb, ws);
    gru_mfma_kernel<<<128, TPB, 0, stream>>>(bih0, bhh0, bih1, bhh1, Wfc, bfc, out, ws);
  } else {
    int*    bar = (int*)ws;
    float4* A0  = (float4*)(ws + A_OFF);
    float4* A1  = (float4*)(ws + A_OFF + HBUF_BYTES);
    float4* B0  = (float4*)(ws + B_OFF);
    float4* B1  = (float4*)(ws + B_OFF + HBUF_BYTES);
    float4* xe4 = (float4*)(ws + XE_OFF);
    const int use_xe = (ws_size >= (size_t)XE_OFF + XE_BYTES) ? 1 : 0;
    hipMemsetAsync(ws, 0, XE_OFF, stream);
    if (use_xe){
      gather_xe_kernel<<<(S_LEN * 64 * BATCH) / TPB, TPB, 0, stream>>>(x, emb, xe4);
    }
    gru_persist_kernel<<<256, TPB, 0, stream>>>(
        x, emb, Wih0, Whh0, bih0, bhh0, Wih1, Whh1, bih1, bhh1, Wfc, bfc,
        out, bar, A0, A1, B0, B1, xe4, use_xe);
  }
}

// Round 5
// 2643.634 us; speedup vs baseline: 12.2433x; 1.0290x over previous
//
#include <hip/hip_runtime.h>
#include <math.h>

typedef short  s8v __attribute__((ext_vector_type(8)));   // 8 bf16 (4 VGPRs)
typedef float  f4v __attribute__((ext_vector_type(4)));
typedef unsigned int u2v __attribute__((ext_vector_type(2)));

#define S_LEN 512
#define BATCH 64
#define HID   512
#define TPB   256

// ---------------- fast-path workspace layout ----------------
// [0, 8KB): monotonic flags: [l][m][rep8] lines of 128B; dword idx = producer rowWG
#define SYNCF_BYTES 3145728L                 // reserved (flags use first 8KB)
#define WI0H_OFF 3145728L
#define WI0L_OFF (WI0H_OFF + 786432L)
#define WH0H_OFF (WI0L_OFF + 786432L)
#define WH0L_OFF (WH0H_OFF + 1572864L)
#define WI1H_OFF (WH0L_OFF + 1572864L)
#define WI1L_OFF (WI1H_OFF + 1572864L)
#define WH1H_OFF (WI1L_OFF + 1572864L)
#define WH1L_OFF (WH1H_OFF + 1572864L)
#define XEB_OFF  (WH1L_OFF + 1572864L)       // xe bf16 [t*64+b][256]
#define H0B_OFF  (XEB_OFF + 16777216L)       // h0 bf16 [t][b][512]
#define H1B_OFF  (H0B_OFF + 33554432L)
#define NEED_FAST (H1B_OFF + 33554432L)      // 98,041,856

// ---------------- fallback (fence path, R1) layout ----------------
#define BAR_BYTES   4096
#define HBUF_BYTES  (HID*BATCH*4)
#define A_OFF       BAR_BYTES
#define B_OFF       (A_OFF + 2*HBUF_BYTES)
#define XE_OFF      (B_OFF + 2*HBUF_BYTES)
#define XE_BYTES    ((size_t)S_LEN*64*BATCH*16)

__device__ __forceinline__ float fexp2(float x){ return __builtin_amdgcn_exp2f(x); }
__device__ __forceinline__ float frcp (float x){ return __builtin_amdgcn_rcpf(x); }
__device__ __forceinline__ float sigm (float x){ return frcp(1.f + fexp2(-1.44269504089f*x)); }
__device__ __forceinline__ float tanhx(float x){ return 1.f - 2.f*frcp(1.f + fexp2(2.88539008178f*x)); }
__device__ __forceinline__ float sigmoid_f(float v){ return 1.0f/(1.0f + expf(-v)); }

__device__ __forceinline__ unsigned short f2bf(float f){
  unsigned int u = __float_as_uint(f);
  u = u + 0x7FFFu + ((u >> 16) & 1u);          // RNE
  return (unsigned short)(u >> 16);
}
__device__ __forceinline__ float bf2f(unsigned short s){
  return __uint_as_float(((unsigned int)s) << 16);
}

// =====================================================================
// Phase A kernels
// =====================================================================
__global__ void wcvt_kernel(const float* __restrict__ Wih0, const float* __restrict__ Whh0,
                            const float* __restrict__ Wih1, const float* __restrict__ Whh1,
                            char* __restrict__ ws)
{
  int idx = blockIdx.x * TPB + threadIdx.x;    // 2,752,512 total
  const float* src; long hi_off, lo_off; int pos;
  if (idx < 393216)       { src = Wih0; pos = idx;           hi_off = WI0H_OFF; lo_off = WI0L_OFF; }
  else if (idx < 1179648) { src = Whh0; pos = idx - 393216;  hi_off = WH0H_OFF; lo_off = WH0L_OFF; }
  else if (idx < 1966080) { src = Wih1; pos = idx - 1179648; hi_off = WI1H_OFF; lo_off = WI1L_OFF; }
  else                    { src = Whh1; pos = idx - 1966080; hi_off = WH1H_OFF; lo_off = WH1L_OFF; }
  float w = src[pos];
  unsigned short h = f2bf(w);
  unsigned short l = f2bf(w - bf2f(h));
  ((unsigned short*)(ws + hi_off))[pos] = h;
  ((unsigned short*)(ws + lo_off))[pos] = l;
}

__global__ void gather_xe_bf_kernel(const int* __restrict__ x,
                                    const float* __restrict__ emb,
                                    char* __restrict__ ws)
{
  int idx = blockIdx.x * TPB + threadIdx.x;    // 2,097,152 = 32768 n * 64 k4
  int k4 = idx & 63;
  int n  = idx >> 6;
  int t = n >> 6, b = n & 63;
  int tok = x[b * S_LEN + t];
  float4 v = make_float4(0.f,0.f,0.f,0.f);
  if (tok != 0) v = ((const float4*)emb)[(size_t)tok * 64 + k4];
  unsigned int lo = (unsigned int)f2bf(v.x) | ((unsigned int)f2bf(v.y) << 16);
  unsigned int hi = (unsigned int)f2bf(v.z) | ((unsigned int)f2bf(v.w) << 16);
  ((uint2*)(ws + XEB_OFF))[(long)n * 64 + k4] = make_uint2(lo, hi);
}

// =====================================================================
// Flat sync: monotonic per-producer counters, 8 replica lines per (l,m).
// flag value = number of completed ticks by that producer WG.
// Producer: ONE plain relaxed store per replica (no RMW, no per-tick lines).
// Consumer: one coalesced 128B IC load of all 32 flags, spin until all>=target.
// =====================================================================
__device__ __forceinline__ int* flag_line(char* ws, int l, int m, int rep){
  return (int*)(ws + (((l*2 + m)*8 + rep) << 7));
}
__device__ __forceinline__ void poll_flags(char* ws, int l, int m, int rep,
                                           int lane, int target){
  int* fl = flag_line(ws, l, m, rep);
  int v;
  do {
    v = __hip_atomic_load(&fl[lane & 31], __ATOMIC_RELAXED, __HIP_MEMORY_SCOPE_AGENT);
  } while (!__all(v >= target));
  asm volatile("" ::: "memory");               // keep data loads after the poll
}
__device__ __forceinline__ void publish_flag(char* ws, int l, int m, int rowWG, int val){
  #pragma unroll
  for (int rep = 0; rep < 8; ++rep)
    __hip_atomic_store(&flag_line(ws, l, m, rep)[rowWG], val,
                       __ATOMIC_RELAXED, __HIP_MEMORY_SCOPE_AGENT);
}
__device__ __forceinline__ void store_b8_coh(void* p, u2v v){
  asm volatile("global_store_dwordx2 %0, %1, off sc0 sc1" :: "v"(p), "v"(v) : "memory");
}

// =====================================================================
// scan body: one wave's role for the whole 512-tick loop.
// SRCMODE: 0 = xe input (no poll), 1 = self-layer h (poll own, slot t-1),
//          2 = cross h0 (poll L0, slot t)
// =====================================================================
template<int NKS, int SRCMODE>
__device__ __forceinline__ void scan_body(
    int isL1, int rowWG, int bh, int rep, int wave, int lane, int tid, int j0, int b0,
    const s8v* __restrict__ Whi, const s8v* __restrict__ Wlo, int AKs, int k0s,
    const s8v* __restrict__ bsrc, int srcKs,
    const float* __restrict__ bih, const float* __restrict__ bhh,
    char* __restrict__ ws, unsigned short* __restrict__ hout,
    f4v* __restrict__ part)
{
  const int quad = lane >> 4, col = lane & 15;

  // ---- A fragments (hi + lo) ----
  s8v ahi[3][NKS], alo[3][NKS];
  #pragma unroll
  for (int rt = 0; rt < 3; ++rt){
    const int row = rt*512 + j0 + col;
    #pragma unroll
    for (int ks = 0; ks < NKS; ++ks){
      const int e = row*AKs + k0s + ks*4 + quad;
      ahi[rt][ks] = Whi[e];
      alo[rt][ks] = Wlo[e];
    }
  }

  // ---- per-thread gate constants + persistent fp32 h (lane<32) ----
  float cr[4], cz[4], cnx[4], cnh[4], hp[4];
  #pragma unroll
  for (int r4 = 0; r4 < 4; ++r4){
    int j = j0 + wave*4 + r4;
    cr[r4]  = bih[j]      + bhh[j];
    cz[r4]  = bih[512+j]  + bhh[512+j];
    cnx[r4] = bih[1024+j];
    cnh[r4] = bhh[1024+j];
    hp[r4]  = 0.f;
  }

  const int pollLayer = (SRCMODE == 2) ? 0 : isL1;

  for (int t = 0; t < S_LEN; ++t){
    if (SRCMODE == 1){ if (t > 0) poll_flags(ws, pollLayer, bh, rep, lane, t); }
    else if (SRCMODE == 2){        poll_flags(ws, pollLayer, bh, rep, lane, t+1); }

    f4v acc[3][2];
    #pragma unroll
    for (int rt = 0; rt < 3; ++rt){ acc[rt][0] = (f4v)0.f; acc[rt][1] = (f4v)0.f; }

    const bool active = (SRCMODE != 1) || (t > 0);
    if (active){
      const int slot = (SRCMODE == 1) ? (t-1) : t;
      #pragma unroll
      for (int ct = 0; ct < 2; ++ct){
        const int nG = b0 + ct*16 + col;
        const long base = ((long)slot*64 + nG)*srcKs + k0s + quad;
        s8v bf[NKS];
        #pragma unroll
        for (int ks = 0; ks < NKS; ++ks) bf[ks] = bsrc[base + ks*4];
        #pragma unroll
        for (int ks = 0; ks < NKS; ++ks){
          #pragma unroll
          for (int rt = 0; rt < 3; ++rt){
            acc[rt][ct] = __builtin_amdgcn_mfma_f32_16x16x32_bf16(ahi[rt][ks], bf[ks], acc[rt][ct], 0, 0, 0);
            acc[rt][ct] = __builtin_amdgcn_mfma_f32_16x16x32_bf16(alo[rt][ks], bf[ks], acc[rt][ct], 0, 0, 0);
          }
        }
      }
    }

    // ---- partials to LDS ----
    #pragma unroll
    for (int rt = 0; rt < 3; ++rt)
      #pragma unroll
      for (int ct = 0; ct < 2; ++ct)
        part[(wave*6 + rt*2 + ct)*64 + lane] = acc[rt][ct];
    __syncthreads();

    // ---- reduce + gate math (wave = unit-group, lane<32 = local batch) ----
    if (lane < 32){
      const int b = lane;
      const int pl = wave*16 + (b & 15);       // producer lane (quad=wave, col=b&15)
      const int ct = b >> 4;
      f4v sr = (f4v)0.f, sz = (f4v)0.f, snx = (f4v)0.f, snh = (f4v)0.f;
      #pragma unroll
      for (int w = 0; w < 4; ++w){
        const bool inpW = isL1 ? (w < 2) : (w >= 2);
        f4v g0 = part[(w*6 + 0*2 + ct)*64 + pl];
        f4v g1 = part[(w*6 + 1*2 + ct)*64 + pl];
        f4v g2 = part[(w*6 + 2*2 + ct)*64 + pl];
        sr += g0; sz += g1;
        if (inpW) snx += g2; else snh += g2;
      }
      unsigned short hb[4];
      #pragma unroll
      for (int r4 = 0; r4 < 4; ++r4){
        float r = sigm(sr[r4] + cr[r4]);
        float z = sigm(sz[r4] + cz[r4]);
        float n = tanhx(snx[r4] + cnx[r4] + r*(snh[r4] + cnh[r4]));
        float h = n + z*(hp[r4] - n);
        hp[r4] = h;
        hb[r4] = f2bf(h);
      }
      u2v val;
      val.x = (unsigned int)hb[0] | ((unsigned int)hb[1] << 16);
      val.y = (unsigned int)hb[2] | ((unsigned int)hb[3] << 16);
      unsigned short* dst = hout + (((long)t*64 + b0 + b)*512 + j0 + wave*4);
      store_b8_coh((void*)dst, val);
    }
    asm volatile("s_waitcnt vmcnt(0)" ::: "memory");   // h drained to IC
    __syncthreads();
    if (tid == 0) publish_flag(ws, isL1, bh, rowWG, t + 1);
  }
}

// =====================================================================
// Persistent MFMA scan kernel: 128 WGs.
// wg 0..63: layer0, wg 64..127: layer1. lw=wg&63: rowWG=lw>>1, bh=lw&1.
// =====================================================================
__global__ __launch_bounds__(TPB, 1) void gru_mfma_kernel(
    const float* __restrict__ bih0, const float* __restrict__ bhh0,
    const float* __restrict__ bih1, const float* __restrict__ bhh1,
    const float* __restrict__ Wfc,  const float* __restrict__ bfc,
    float* __restrict__ out, char* __restrict__ ws)
{
  __shared__ f4v part[4*6*64];                 // 24 KB partial-reduce buffer

  const int tid  = threadIdx.x;
  const int wg   = blockIdx.x;
  const int lane = tid & 63;
  const int wave = tid >> 6;
  const int isL1 = (wg >= 64);
  const int lw   = wg & 63;
  const int rowWG = lw >> 1;
  const int bh    = lw & 1;
  const int rep   = lw & 7;
  const int j0 = rowWG * 16;
  const int b0 = bh * 32;

  const s8v* wi0h = (const s8v*)(ws + WI0H_OFF); const s8v* wi0l = (const s8v*)(ws + WI0L_OFF);
  const s8v* wh0h = (const s8v*)(ws + WH0H_OFF); const s8v* wh0l = (const s8v*)(ws + WH0L_OFF);
  const s8v* wi1h = (const s8v*)(ws + WI1H_OFF); const s8v* wi1l = (const s8v*)(ws + WI1L_OFF);
  const s8v* wh1h = (const s8v*)(ws + WH1H_OFF); const s8v* wh1l = (const s8v*)(ws + WH1L_OFF);
  const s8v* xeb = (const s8v*)(ws + XEB_OFF);
  const s8v* h0b = (const s8v*)(ws + H0B_OFF);
  const s8v* h1b = (const s8v*)(ws + H1B_OFF);
  unsigned short* h0o = (unsigned short*)(ws + H0B_OFF);
  unsigned short* h1o = (unsigned short*)(ws + H1B_OFF);

  if (!isL1){
    if (wave < 2)
      scan_body<8,1>(isL1, rowWG, bh, rep, wave, lane, tid, j0, b0,
                     wh0h, wh0l, 64, wave*32, h0b, 64, bih0, bhh0, ws, h0o, part);
    else
      scan_body<4,0>(isL1, rowWG, bh, rep, wave, lane, tid, j0, b0,
                     wi0h, wi0l, 32, (wave-2)*16, xeb, 32, bih0, bhh0, ws, h0o, part);
  } else {
    if (wave < 2)
      scan_body<8,2>(isL1, rowWG, bh, rep, wave, lane, tid, j0, b0,
                     wi1h, wi1l, 64, wave*32, h0b, 64, bih1, bhh1, ws, h1o, part);
    else
      scan_body<8,1>(isL1, rowWG, bh, rep, wave, lane, tid, j0, b0,
                     wh1h, wh1l, 64, (wave-2)*32, h1b, 64, bih1, bhh1, ws, h1o, part);
  }

  // ---- epilogue FC: out[b] = sigmoid(h1_511 . Wfc + bfc) ----
  if (wg == 64 && wave == 0){
    poll_flags(ws, 1, 0, 0, lane, S_LEN);
    poll_flags(ws, 1, 1, 1, lane, S_LEN);
    float acc = bfc[0];
    const s8v* h1v = h1b + ((long)511*64 + lane)*64;
    const float4* wf = (const float4*)Wfc;
    #pragma unroll 4
    for (int kk = 0; kk < 64; ++kk){
      s8v hv = h1v[kk];
      float4 w0 = wf[kk*2], w1 = wf[kk*2+1];
      acc += bf2f((unsigned short)hv[0])*w0.x + bf2f((unsigned short)hv[1])*w0.y
           + bf2f((unsigned short)hv[2])*w0.z + bf2f((unsigned short)hv[3])*w0.w
           + bf2f((unsigned short)hv[4])*w1.x + bf2f((unsigned short)hv[5])*w1.y
           + bf2f((unsigned short)hv[6])*w1.z + bf2f((unsigned short)hv[7])*w1.w;
    }
    out[lane] = sigm(acc);
  }
}

// =====================================================================
// FALLBACK (R1 fence path) — only if ws too small for the fast path.
// =====================================================================
__global__ void gather_xe_kernel(const int* __restrict__ x,
                                 const float* __restrict__ emb,
                                 float4* __restrict__ xe4)
{
  int idx = blockIdx.x * TPB + threadIdx.x;
  int b  = idx & 63;
  int k4 = (idx >> 6) & 63;
  int t  = idx >> 12;
  int tok = x[b * S_LEN + t];
  float4 v = make_float4(0.f, 0.f, 0.f, 0.f);
  if (tok != 0) v = ((const float4*)emb)[(size_t)tok * 64 + k4];
  xe4[idx] = v;
}

__device__ __forceinline__ void accum_vec(const float4* __restrict__ xin,
                                          const float4* __restrict__ w0,
                                          const float4* __restrict__ w1,
                                          const float4* __restrict__ w2,
                                          int n4, int lane,
                                          float& ar, float& az, float& an)
{
  #pragma unroll 4
  for (int k = 0; k < n4; ++k){
    float4 xv = xin[k * 64 + lane];
    float4 wr = w0[k], wz = w1[k], wn = w2[k];
    ar = fmaf(xv.x, wr.x, ar); az = fmaf(xv.x, wz.x, az); an = fmaf(xv.x, wn.x, an);
    ar = fmaf(xv.y, wr.y, ar); az = fmaf(xv.y, wz.y, az); an = fmaf(xv.y, wn.y, an);
    ar = fmaf(xv.z, wr.z, ar); az = fmaf(xv.z, wz.z, az); an = fmaf(xv.z, wn.z, an);
    ar = fmaf(xv.w, wr.w, ar); az = fmaf(xv.w, wz.w, az); an = fmaf(xv.w, wn.w, an);
  }
}

__device__ __forceinline__ void accum_emb(const int* __restrict__ x,
                                          const float* __restrict__ emb, int t,
                                          const float4* __restrict__ w0,
                                          const float4* __restrict__ w1,
                                          const float4* __restrict__ w2,
                                          int lane, float& ar, float& az, float& an)
{
  int tok = x[lane * S_LEN + t];
  const float4* erow = (const float4*)emb + (size_t)tok * 64;
  float m = (tok != 0) ? 1.0f : 0.0f;
  #pragma unroll 4
  for (int k = 0; k < 64; ++k){
    float4 xv = erow[k];
    float xx = xv.x*m, xy = xv.y*m, xz = xv.z*m, xw = xv.w*m;
    float4 wr = w0[k], wz = w1[k], wn = w2[k];
    ar = fmaf(xx, wr.x, ar); az = fmaf(xx, wz.x, az); an = fmaf(xx, wn.x, an);
    ar = fmaf(xy, wr.y, ar); az = fmaf(xy, wz.y, az); an = fmaf(xy, wn.y, an);
    ar = fmaf(xz, wr.z, ar); az = fmaf(xz, wz.z, az); an = fmaf(xz, wn.z, an);
    ar = fmaf(xw, wr.w, ar); az = fmaf(xw, wz.w, az); an = fmaf(xw, wn.w, an);
  }
}

__device__ __forceinline__ void stage_weights(float4* wlds, int tid, int j0, int kin4,
                                              const float* Wih, const float* Whh)
{
  const int per = 3 * (kin4 + 128);
  for (int idx = tid; idx < 4 * per; idx += TPB){
    int w = idx / per, rem = idx - w * per;
    int g = rem / (kin4 + 128), k = rem - g * (kin4 + 128);
    int row = g * HID + j0 + w;
    float4 v;
    if (k < kin4) v = ((const float4*)Wih)[(size_t)row * kin4 + k];
    else          v = ((const float4*)Whh)[(size_t)row * 128 + (k - kin4)];
    wlds[(w * 3 + g) * 256 + k] = v;
  }
}

__device__ __forceinline__ void barrier_tick(int* bar, int wg, int tid, int phase)
{
  __syncthreads();
  if (tid == 0){
    __builtin_amdgcn_fence(__ATOMIC_RELEASE, "agent");
    int* leaf = bar + 32 + (wg >> 4) * 32;
    int old = __hip_atomic_fetch_add(leaf, 1, __ATOMIC_ACQ_REL, __HIP_MEMORY_SCOPE_AGENT);
    if (old == phase * 16 + 15){
      __hip_atomic_fetch_add(bar, 1, __ATOMIC_ACQ_REL, __HIP_MEMORY_SCOPE_AGENT);
    }
    const int target = (phase + 1) * 16;
    while (__hip_atomic_load(bar, __ATOMIC_ACQUIRE, __HIP_MEMORY_SCOPE_AGENT) < target){
      __builtin_amdgcn_s_sleep(2);
    }
    __builtin_amdgcn_fence(__ATOMIC_ACQUIRE, "agent");
  }
  __syncthreads();
}

__device__ __forceinline__ void finish_store(const float4* __restrict__ hprev,
                                             float ar, float az, float anx, float anh,
                                             int lane, int j, float4* __restrict__ hout)
{
  float r  = sigmoid_f(ar);
  float zz = sigmoid_f(az);
  float n  = tanhf(fmaf(r, anh, anx));
  int fi = ((j >> 2) * 64 + lane) * 4 + (j & 3);
  float hhp = ((const float*)hprev)[fi];
  ((float*)hout)[fi] = fmaf(zz, hhp - n, n);
}

__global__ __launch_bounds__(TPB) void gru_persist_kernel(
    const int*   __restrict__ x,    const float* __restrict__ emb,
    const float* __restrict__ Wih0, const float* __restrict__ Whh0,
    const float* __restrict__ bih0, const float* __restrict__ bhh0,
    const float* __restrict__ Wih1, const float* __restrict__ Whh1,
    const float* __restrict__ bih1, const float* __restrict__ bhh1,
    const float* __restrict__ Wfc,  const float* __restrict__ bfc,
    float* __restrict__ out, int* __restrict__ bar,
    float4* __restrict__ A0, float4* __restrict__ A1,
    float4* __restrict__ B0, float4* __restrict__ B1,
    const float4* __restrict__ xe4, int use_xe)
{
  __shared__ float4 wlds[3072];
  const int tid  = threadIdx.x;
  const int wg   = blockIdx.x;
  const int lane = tid & 63;
  const int wave = tid >> 6;
  const bool isL1 = (wg >= 128);
  const int j0   = (isL1 ? wg - 128 : wg) * 4;
  const int kin4 = isL1 ? 128 : 64;

  stage_weights(wlds, tid, j0, kin4, isL1 ? Wih1 : Wih0, isL1 ? Whh1 : Whh0);
  __syncthreads();

  const int j = j0 + wave;
  const float* bih = isL1 ? bih1 : bih0;
  const float* bhh = isL1 ? bhh1 : bhh0;
  const float br  = bih[j]        + bhh[j];
  const float bz  = bih[j + 512]  + bhh[j + 512];
  const float bnx = bih[j + 1024];
  const float bnh = bhh[j + 1024];

  const float4* w0 = &wlds[(wave * 3 + 0) * 256];
  const float4* w1 = &wlds[(wave * 3 + 1) * 256];
  const float4* w2 = &wlds[(wave * 3 + 2) * 256];

  float4* A[2] = {A0, A1};
  float4* B[2] = {B0, B1};

  for (int t = 0; t <= S_LEN; ++t){
    if (!isL1){
      if (t < S_LEN){
        const float4* hprev = A[(t + 1) & 1];
        float ar = br, az = bz, anx = bnx, anh = bnh;
        if (use_xe) accum_vec(xe4 + (size_t)t * 4096, w0, w1, w2, 64, lane, ar, az, anx);
        else        accum_emb(x, emb, t, w0, w1, w2, lane, ar, az, anx);
        accum_vec(hprev, w0 + 64, w1 + 64, w2 + 64, 128, lane, ar, az, anh);
        finish_store(hprev, ar, az, anx, anh, lane, j, A[t & 1]);
      }
    } else if (t >= 1){
      const int u = t - 1;
      const float4* xin   = A[u & 1];
      const float4* hprev = B[(u + 1) & 1];
      float ar = br, az = bz, anx = bnx, anh = bnh;
      accum_vec(xin,   w0,       w1,       w2,       128, lane, ar, az, anx);
      accum_vec(hprev, w0 + 128, w1 + 128, w2 + 128, 128, lane, ar, az, anh);
      finish_store(hprev, ar, az, anx, anh, lane, j, B[u & 1]);
    }
    barrier_tick(bar, wg, tid, t);
  }

  if (wg == 0 && wave == 0){
    float acc = bfc[0];
    const float4* h1 = B[1];
    const float4* wf = (const float4*)Wfc;
    #pragma unroll 4
    for (int k = 0; k < 128; ++k){
      float4 hv = h1[k * 64 + lane];
      float4 wv = wf[k];
      acc = fmaf(hv.x, wv.x, acc); acc = fmaf(hv.y, wv.y, acc);
      acc = fmaf(hv.z, wv.z, acc); acc = fmaf(hv.w, wv.w, acc);
    }
    out[lane] = sigmoid_f(acc);
  }
}

extern "C" void kernel_launch(void* const* d_in, const int* in_sizes, int n_in,
                              void* d_out, int out_size, void* d_ws, size_t ws_size,
                              hipStream_t stream)
{
  (void)in_sizes; (void)n_in; (void)out_size;
  const int*   x    = (const int*)  d_in[0];
  const float* emb  = (const float*)d_in[1];
  const float* Wih0 = (const float*)d_in[2];
  const float* Whh0 = (const float*)d_in[3];
  const float* bih0 = (const float*)d_in[4];
  const float* bhh0 = (const float*)d_in[5];
  const float* Wih1 = (const float*)d_in[6];
  const float* Whh1 = (const float*)d_in[7];
  const float* bih1 = (const float*)d_in[8];
  const float* bhh1 = (const float*)d_in[9];
  const float* Wfc  = (const float*)d_in[10];
  const float* bfc  = (const float*)d_in[11];
  float* out = (float*)d_out;
  char* ws = (char*)d_ws;

  if (ws_size >= (size_t)NEED_FAST){
    hipMemsetAsync(ws, 0, 8192, stream);                 // monotonic flags
    wcvt_kernel<<<2752512 / TPB, TPB, 0, stream>>>(Wih0, Whh0, Wih1, Whh1, ws);
    gather_xe_bf_kernel<<<2097152 / TPB, TPB, 0, stream>>>(x, emb, ws);
    gru_mfma_kernel<<<128, TPB, 0, stream>>>(bih0, bhh0, bih1, bhh1, Wfc, bfc, out, ws);
  } else {
    int*    bar = (int*)ws;
    float4* A0  = (float4*)(ws + A_OFF);
    float4* A1  = (float4*)(ws + A_OFF + HBUF_BYTES);
    float4* B0  = (float4*)(ws + B_OFF);
    float4* B1  = (float4*)(ws + B_OFF + HBUF_BYTES);
    float4* xe4 = (float4*)(ws + XE_OFF);
    const int use_xe = (ws_size >= (size_t)XE_OFF + XE_BYTES) ? 1 : 0;
    hipMemsetAsync(ws, 0, XE_OFF, stream);
    if (use_xe){
      gather_xe_kernel<<<(S_LEN * 64 * BATCH) / TPB, TPB, 0, stream>>>(x, emb, xe4);
    }
    gru_persist_kernel<<<256, TPB, 0, stream>>>(
        x, emb, Wih0, Whh0, bih0, bhh0, Wih1, Whh1, bih1, bhh1, Wfc, bfc,
        out, bar, A0, A1, B0, B1, xe4, use_xe);
  }
}

// Round 6
// 2035.502 us; speedup vs baseline: 15.9011x; 1.2988x over previous
//
#include <hip/hip_runtime.h>
#include <math.h>

typedef short  s8v __attribute__((ext_vector_type(8)));   // 8 bf16 (4 VGPRs)
typedef float  f4v __attribute__((ext_vector_type(4)));
typedef unsigned long long ull;

#define S_LEN 512
#define BATCH 64
#define HID   512
#define TPB   256

// ---------------- fast-path workspace layout ----------------
// weights (bf16 hi/lo), then xe bf16, then tagged h records.
// h record = {2 x bf16 (low dword) | tag = tick+1 (high dword)}, 8B, layout [slot][rec 256][b 64]
#define WI0H_OFF 0L
#define WI0L_OFF 786432L
#define WH0H_OFF 1572864L
#define WH0L_OFF 3145728L
#define WI1H_OFF 4718592L
#define WI1L_OFF 6291456L
#define WH1H_OFF 7864320L
#define WH1L_OFF 9437184L
#define XEB_OFF  11010048L                   // xe bf16 [t*64+b][256]
#define H0R_OFF  27787264L                   // 512 slots x 16384 ull
#define H1R_OFF  94896128L                   // 4 slots x 16384 ull (self-chain lag <= 1)
#define NEED_FAST 95420416L

// ---------------- fallback (fence path, R1) layout ----------------
#define BAR_BYTES   4096
#define HBUF_BYTES  (HID*BATCH*4)
#define A_OFF       BAR_BYTES
#define B_OFF       (A_OFF + 2*HBUF_BYTES)
#define XE_OFF      (B_OFF + 2*HBUF_BYTES)
#define XE_BYTES    ((size_t)S_LEN*64*BATCH*16)

__device__ __forceinline__ float fexp2(float x){ return __builtin_amdgcn_exp2f(x); }
__device__ __forceinline__ float frcp (float x){ return __builtin_amdgcn_rcpf(x); }
__device__ __forceinline__ float sigm (float x){ return frcp(1.f + fexp2(-1.44269504089f*x)); }
__device__ __forceinline__ float tanhx(float x){ return 1.f - 2.f*frcp(1.f + fexp2(2.88539008178f*x)); }
__device__ __forceinline__ float sigmoid_f(float v){ return 1.0f/(1.0f + expf(-v)); }

__device__ __forceinline__ unsigned short f2bf(float f){
  unsigned int u = __float_as_uint(f);
  u = u + 0x7FFFu + ((u >> 16) & 1u);          // RNE
  return (unsigned short)(u >> 16);
}
__device__ __forceinline__ float bf2f(unsigned short s){
  return __uint_as_float(((unsigned int)s) << 16);
}

// =====================================================================
// Phase A kernels
// =====================================================================
__global__ void wcvt_kernel(const float* __restrict__ Wih0, const float* __restrict__ Whh0,
                            const float* __restrict__ Wih1, const float* __restrict__ Whh1,
                            char* __restrict__ ws)
{
  int idx = blockIdx.x * TPB + threadIdx.x;    // 2,752,512 total
  const float* src; long hi_off, lo_off; int pos;
  if (idx < 393216)       { src = Wih0; pos = idx;           hi_off = WI0H_OFF; lo_off = WI0L_OFF; }
  else if (idx < 1179648) { src = Whh0; pos = idx - 393216;  hi_off = WH0H_OFF; lo_off = WH0L_OFF; }
  else if (idx < 1966080) { src = Wih1; pos = idx - 1179648; hi_off = WI1H_OFF; lo_off = WI1L_OFF; }
  else                    { src = Whh1; pos = idx - 1966080; hi_off = WH1H_OFF; lo_off = WH1L_OFF; }
  float w = src[pos];
  unsigned short h = f2bf(w);
  unsigned short l = f2bf(w - bf2f(h));
  ((unsigned short*)(ws + hi_off))[pos] = h;
  ((unsigned short*)(ws + lo_off))[pos] = l;
}

__global__ void gather_xe_bf_kernel(const int* __restrict__ x,
                                    const float* __restrict__ emb,
                                    char* __restrict__ ws)
{
  int idx = blockIdx.x * TPB + threadIdx.x;    // 2,097,152 = 32768 n * 64 k4
  int k4 = idx & 63;
  int n  = idx >> 6;
  int t = n >> 6, b = n & 63;
  int tok = x[b * S_LEN + t];
  float4 v = make_float4(0.f,0.f,0.f,0.f);
  if (tok != 0) v = ((const float4*)emb)[(size_t)tok * 64 + k4];
  unsigned int lo = (unsigned int)f2bf(v.x) | ((unsigned int)f2bf(v.y) << 16);
  unsigned int hi = (unsigned int)f2bf(v.z) | ((unsigned int)f2bf(v.w) << 16);
  ((uint2*)(ws + XEB_OFF))[(long)n * 64 + k4] = make_uint2(lo, hi);
}

// =====================================================================
// Tagged-record primitives. Record = 8B {2xbf16 | tag}. Single-sector 8B
// atomic load/store => no tearing; tag==want validates the data in the SAME
// transaction. Poison 0xAAAAAAAA never equals a valid tag (1..512).
// =====================================================================
__device__ __forceinline__ void st_rec(ull* p, ull v){
  __hip_atomic_store(p, v, __ATOMIC_RELAXED, __HIP_MEMORY_SCOPE_AGENT);
}

// fetch+validate one ct-halve of B fragments (NKS s8v) for this lane.
template<int NKS>
__device__ __forceinline__ void load_ct(const ull* __restrict__ sl, int b,
                                        int quad, int k0s, unsigned want,
                                        s8v* __restrict__ bf)
{
  ull d[NKS][4];
  for (;;){
    #pragma unroll
    for (int ks = 0; ks < NKS; ++ks){
      const int e = k0s + ks*4 + quad;             // s8v index -> units [8e,8e+8)
      const ull* p = sl + (long)(4*e)*64 + b;      // recs 4e..4e+3, [rec][b]
      #pragma unroll
      for (int i = 0; i < 4; ++i)
        d[ks][i] = __hip_atomic_load(p + (long)i*64, __ATOMIC_RELAXED, __HIP_MEMORY_SCOPE_AGENT);
    }
    bool ok = true;
    #pragma unroll
    for (int ks = 0; ks < NKS; ++ks)
      #pragma unroll
      for (int i = 0; i < 4; ++i)
        ok = ok && ((unsigned)(d[ks][i] >> 32) == want);
    if (__all(ok)) break;
    __builtin_amdgcn_s_sleep(1);
  }
  #pragma unroll
  for (int ks = 0; ks < NKS; ++ks){
    s8v v;
    #pragma unroll
    for (int i = 0; i < 4; ++i){
      unsigned lo = (unsigned)d[ks][i];
      v[2*i]   = (short)(lo & 0xFFFFu);
      v[2*i+1] = (short)(lo >> 16);
    }
    bf[ks] = v;
  }
}

// =====================================================================
// scan body: one wave's role for the whole 512-tick loop.
// ROLE: 0 = xe input (plain loads), 1 = self-layer hidden (tagged, slot (t-1)&mask,
//       want t), 2 = cross h0 input (tagged, slot t, want t+1)
// =====================================================================
template<int NKS, int ROLE>
__device__ __forceinline__ void scan_body(
    int isL1, int rowWG, int bh, int wave, int lane, int tid, int j0, int b0,
    const s8v* __restrict__ Whi, const s8v* __restrict__ Wlo, int AKs, int k0s,
    const s8v* __restrict__ xsrc,
    const ull* __restrict__ rsrc, int slotMask,
    const float* __restrict__ bih, const float* __restrict__ bhh,
    ull* __restrict__ rout, int outMask,
    f4v* __restrict__ part)
{
  const int quad = lane >> 4, col = lane & 15;

  // ---- A fragments (hi + lo), resident across all 512 ticks ----
  s8v ahi[3][NKS], alo[3][NKS];
  #pragma unroll
  for (int rt = 0; rt < 3; ++rt){
    const int row = rt*512 + j0 + col;
    #pragma unroll
    for (int ks = 0; ks < NKS; ++ks){
      const int e = row*AKs + k0s + ks*4 + quad;
      ahi[rt][ks] = Whi[e];
      alo[rt][ks] = Wlo[e];
    }
  }

  // ---- per-thread gate constants + persistent fp32 h (lane<32) ----
  float cr[4], cz[4], cnx[4], cnh[4], hp[4];
  #pragma unroll
  for (int r4 = 0; r4 < 4; ++r4){
    int j = j0 + wave*4 + r4;
    cr[r4]  = bih[j]      + bhh[j];
    cz[r4]  = bih[512+j]  + bhh[512+j];
    cnx[r4] = bih[1024+j];
    cnh[r4] = bhh[1024+j];
    hp[r4]  = 0.f;
  }

  for (int t = 0; t < S_LEN; ++t){
    f4v acc[3][2];
    #pragma unroll
    for (int rt = 0; rt < 3; ++rt){ acc[rt][0] = (f4v)0.f; acc[rt][1] = (f4v)0.f; }

    const bool active = (ROLE != 1) || (t > 0);
    if (active){
      const ull* sl = (ROLE == 1) ? rsrc + (long)((t-1) & slotMask)*16384
                                  : rsrc + (long)(t & slotMask)*16384;
      const unsigned want = (ROLE == 1) ? (unsigned)t : (unsigned)(t+1);
      #pragma unroll
      for (int ct = 0; ct < 2; ++ct){
        s8v bf[NKS];
        if (ROLE == 0){
          const int nG = b0 + ct*16 + col;
          const long base = ((long)t*64 + nG)*32 + k0s + quad;   // xe: 32 s8v per row
          #pragma unroll
          for (int ks = 0; ks < NKS; ++ks) bf[ks] = xsrc[base + ks*4];
        } else {
          load_ct<NKS>(sl, b0 + ct*16 + col, quad, k0s, want, bf);
        }
        #pragma unroll
        for (int ks = 0; ks < NKS; ++ks)
          #pragma unroll
          for (int rt = 0; rt < 3; ++rt){
            acc[rt][ct] = __builtin_amdgcn_mfma_f32_16x16x32_bf16(ahi[rt][ks], bf[ks], acc[rt][ct], 0, 0, 0);
            acc[rt][ct] = __builtin_amdgcn_mfma_f32_16x16x32_bf16(alo[rt][ks], bf[ks], acc[rt][ct], 0, 0, 0);
          }
      }
    }

    // ---- partials to LDS ----
    #pragma unroll
    for (int rt = 0; rt < 3; ++rt)
      #pragma unroll
      for (int ct = 0; ct < 2; ++ct)
        part[(wave*6 + rt*2 + ct)*64 + lane] = acc[rt][ct];
    __syncthreads();

    // ---- reduce + gate math + tagged h store (wave = unit-group, lane<32 = b) ----
    if (lane < 32){
      const int b = lane;
      const int pl = wave*16 + (b & 15);
      const int ct = b >> 4;
      f4v sr = (f4v)0.f, sz = (f4v)0.f, snx = (f4v)0.f, snh = (f4v)0.f;
      #pragma unroll
      for (int w = 0; w < 4; ++w){
        const bool inpW = isL1 ? (w < 2) : (w >= 2);
        f4v g0 = part[(w*6 + 0*2 + ct)*64 + pl];
        f4v g1 = part[(w*6 + 1*2 + ct)*64 + pl];
        f4v g2 = part[(w*6 + 2*2 + ct)*64 + pl];
        sr += g0; sz += g1;
        if (inpW) snx += g2; else snh += g2;
      }
      unsigned short hb[4];
      #pragma unroll
      for (int r4 = 0; r4 < 4; ++r4){
        float r = sigm(sr[r4] + cr[r4]);
        float z = sigm(sz[r4] + cz[r4]);
        float n = tanhx(snx[r4] + cnx[r4] + r*(snh[r4] + cnh[r4]));
        float h = n + z*(hp[r4] - n);
        hp[r4] = h;
        hb[r4] = f2bf(h);
      }
      const int slotw = t & outMask;
      const ull tg = ((ull)(unsigned)(t + 1)) << 32;
      ull* ob = rout + (long)slotw*16384 + (long)(rowWG*8 + wave*2)*64 + (b0 + b);
      st_rec(ob,      ((ull)((unsigned)hb[0] | ((unsigned)hb[1] << 16))) | tg);
      st_rec(ob + 64, ((ull)((unsigned)hb[2] | ((unsigned)hb[3] << 16))) | tg);
    }
    __syncthreads();                         // partial buffer reuse next tick
  }
}

// =====================================================================
// Persistent MFMA scan kernel: 128 WGs.
// wg 0..63: layer0, wg 64..127: layer1. lw=wg&63: rowWG=lw>>1, bh=lw&1.
// L0: waves 0-1 hidden (h0 tagged), waves 2-3 xe input (plain).
// L1: waves 0-1 input (h0 tagged, cross), waves 2-3 hidden (h1 tagged, 4-slot ring).
// =====================================================================
__global__ __launch_bounds__(TPB, 1) void gru_mfma_kernel(
    const float* __restrict__ bih0, const float* __restrict__ bhh0,
    const float* __restrict__ bih1, const float* __restrict__ bhh1,
    const float* __restrict__ Wfc,  const float* __restrict__ bfc,
    float* __restrict__ out, char* __restrict__ ws)
{
  __shared__ f4v part[4*6*64];                 // 24 KB partial-reduce buffer

  const int tid  = threadIdx.x;
  const int wg   = blockIdx.x;
  const int lane = tid & 63;
  const int wave = tid >> 6;
  const int isL1 = (wg >= 64);
  const int lw   = wg & 63;
  const int rowWG = lw >> 1;
  const int bh    = lw & 1;
  const int j0 = rowWG * 16;
  const int b0 = bh * 32;

  const s8v* wi0h = (const s8v*)(ws + WI0H_OFF); const s8v* wi0l = (const s8v*)(ws + WI0L_OFF);
  const s8v* wh0h = (const s8v*)(ws + WH0H_OFF); const s8v* wh0l = (const s8v*)(ws + WH0L_OFF);
  const s8v* wi1h = (const s8v*)(ws + WI1H_OFF); const s8v* wi1l = (const s8v*)(ws + WI1L_OFF);
  const s8v* wh1h = (const s8v*)(ws + WH1H_OFF); const s8v* wh1l = (const s8v*)(ws + WH1L_OFF);
  const s8v* xeb = (const s8v*)(ws + XEB_OFF);
  const ull* h0r = (const ull*)(ws + H0R_OFF);
  const ull* h1r = (const ull*)(ws + H1R_OFF);
  ull* h0w = (ull*)(ws + H0R_OFF);
  ull* h1w = (ull*)(ws + H1R_OFF);

  if (!isL1){
    if (wave < 2)
      scan_body<8,1>(isL1, rowWG, bh, wave, lane, tid, j0, b0,
                     wh0h, wh0l, 64, wave*32, xeb, h0r, 0x3FFFFFFF,
                     bih0, bhh0, h0w, 0x3FFFFFFF, part);
    else
      scan_body<4,0>(isL1, rowWG, bh, wave, lane, tid, j0, b0,
                     wi0h, wi0l, 32, (wave-2)*16, xeb, h0r, 0x3FFFFFFF,
                     bih0, bhh0, h0w, 0x3FFFFFFF, part);
  } else {
    if (wave < 2)
      scan_body<8,2>(isL1, rowWG, bh, wave, lane, tid, j0, b0,
                     wi1h, wi1l, 64, wave*32, xeb, h0r, 0x3FFFFFFF,
                     bih1, bhh1, h1w, 3, part);
    else
      scan_body<8,1>(isL1, rowWG, bh, wave, lane, tid, j0, b0,
                     wh1h, wh1l, 64, (wave-2)*32, xeb, h1r, 3,
                     bih1, bhh1, h1w, 3, part);
  }

  // ---- epilogue FC: out[b] = sigmoid(h1_511 . Wfc + bfc), tag-validated ----
  if (wg == 64 && wave == 0){
    const ull* sl = h1r + 3L*16384;            // slot 511 & 3 == 3, tag 512
    float acc = bfc[0];
    for (int c0 = 0; c0 < 256; c0 += 32){
      ull d[32];
      for (;;){
        #pragma unroll
        for (int i = 0; i < 32; ++i)
          d[i] = __hip_atomic_load(sl + (long)(c0+i)*64 + lane,
                                   __ATOMIC_RELAXED, __HIP_MEMORY_SCOPE_AGENT);
        bool ok = true;
        #pragma unroll
        for (int i = 0; i < 32; ++i) ok = ok && ((unsigned)(d[i] >> 32) == 512u);
        if (__all(ok)) break;
        __builtin_amdgcn_s_sleep(1);
      }
      #pragma unroll
      for (int i = 0; i < 32; ++i){
        unsigned lo = (unsigned)d[i];
        int u = (c0 + i) * 2;
        acc += bf2f((unsigned short)(lo & 0xFFFFu)) * Wfc[u]
             + bf2f((unsigned short)(lo >> 16))     * Wfc[u+1];
      }
    }
    out[lane] = sigm(acc);
  }
}

// =====================================================================
// FALLBACK (R1 fence path) — only if ws too small for the fast path.
// =====================================================================
__global__ void gather_xe_kernel(const int* __restrict__ x,
                                 const float* __restrict__ emb,
                                 float4* __restrict__ xe4)
{
  int idx = blockIdx.x * TPB + threadIdx.x;
  int b  = idx & 63;
  int k4 = (idx >> 6) & 63;
  int t  = idx >> 12;
  int tok = x[b * S_LEN + t];
  float4 v = make_float4(0.f, 0.f, 0.f, 0.f);
  if (tok != 0) v = ((const float4*)emb)[(size_t)tok * 64 + k4];
  xe4[idx] = v;
}

__device__ __forceinline__ void accum_vec(const float4* __restrict__ xin,
                                          const float4* __restrict__ w0,
                                          const float4* __restrict__ w1,
                                          const float4* __restrict__ w2,
                                          int n4, int lane,
                                          float& ar, float& az, float& an)
{
  #pragma unroll 4
  for (int k = 0; k < n4; ++k){
    float4 xv = xin[k * 64 + lane];
    float4 wr = w0[k], wz = w1[k], wn = w2[k];
    ar = fmaf(xv.x, wr.x, ar); az = fmaf(xv.x, wz.x, az); an = fmaf(xv.x, wn.x, an);
    ar = fmaf(xv.y, wr.y, ar); az = fmaf(xv.y, wz.y, az); an = fmaf(xv.y, wn.y, an);
    ar = fmaf(xv.z, wr.z, ar); az = fmaf(xv.z, wz.z, az); an = fmaf(xv.z, wn.z, an);
    ar = fmaf(xv.w, wr.w, ar); az = fmaf(xv.w, wz.w, az); an = fmaf(xv.w, wn.w, an);
  }
}

__device__ __forceinline__ void accum_emb(const int* __restrict__ x,
                                          const float* __restrict__ emb, int t,
                                          const float4* __restrict__ w0,
                                          const float4* __restrict__ w1,
                                          const float4* __restrict__ w2,
                                          int lane, float& ar, float& az, float& an)
{
  int tok = x[lane * S_LEN + t];
  const float4* erow = (const float4*)emb + (size_t)tok * 64;
  float m = (tok != 0) ? 1.0f : 0.0f;
  #pragma unroll 4
  for (int k = 0; k < 64; ++k){
    float4 xv = erow[k];
    float xx = xv.x*m, xy = xv.y*m, xz = xv.z*m, xw = xv.w*m;
    float4 wr = w0[k], wz = w1[k], wn = w2[k];
    ar = fmaf(xx, wr.x, ar); az = fmaf(xx, wz.x, az); an = fmaf(xx, wn.x, an);
    ar = fmaf(xy, wr.y, ar); az = fmaf(xy, wz.y, az); an = fmaf(xy, wn.y, an);
    ar = fmaf(xz, wr.z, ar); az = fmaf(xz, wz.z, az); an = fmaf(xz, wn.z, an);
    ar = fmaf(xw, wr.w, ar); az = fmaf(xw, wz.w, az); an = fmaf(xw, wn.w, an);
  }
}

__device__ __forceinline__ void stage_weights(float4* wlds, int tid, int j0, int kin4,
                                              const float* Wih, const float* Whh)
{
  const int per = 3 * (kin4 + 128);
  for (int idx = tid; idx < 4 * per; idx += TPB){
    int w = idx / per, rem = idx - w * per;
    int g = rem / (kin4 + 128), k = rem - g * (kin4 + 128);
    int row = g * HID + j0 + w;
    float4 v;
    if (k < kin4) v = ((const float4*)Wih)[(size_t)row * kin4 + k];
    else          v = ((const float4*)Whh)[(size_t)row * 128 + (k - kin4)];
    wlds[(w * 3 + g) * 256 + k] = v;
  }
}

__device__ __forceinline__ void barrier_tick(int* bar, int wg, int tid, int phase)
{
  __syncthreads();
  if (tid == 0){
    __builtin_amdgcn_fence(__ATOMIC_RELEASE, "agent");
    int* leaf = bar + 32 + (wg >> 4) * 32;
    int old = __hip_atomic_fetch_add(leaf, 1, __ATOMIC_ACQ_REL, __HIP_MEMORY_SCOPE_AGENT);
    if (old == phase * 16 + 15){
      __hip_atomic_fetch_add(bar, 1, __ATOMIC_ACQ_REL, __HIP_MEMORY_SCOPE_AGENT);
    }
    const int target = (phase + 1) * 16;
    while (__hip_atomic_load(bar, __ATOMIC_ACQUIRE, __HIP_MEMORY_SCOPE_AGENT) < target){
      __builtin_amdgcn_s_sleep(2);
    }
    __builtin_amdgcn_fence(__ATOMIC_ACQUIRE, "agent");
  }
  __syncthreads();
}

__device__ __forceinline__ void finish_store(const float4* __restrict__ hprev,
                                             float ar, float az, float anx, float anh,
                                             int lane, int j, float4* __restrict__ hout)
{
  float r  = sigmoid_f(ar);
  float zz = sigmoid_f(az);
  float n  = tanhf(fmaf(r, anh, anx));
  int fi = ((j >> 2) * 64 + lane) * 4 + (j & 3);
  float hhp = ((const float*)hprev)[fi];
  ((float*)hout)[fi] = fmaf(zz, hhp - n, n);
}

__global__ __launch_bounds__(TPB) void gru_persist_kernel(
    const int*   __restrict__ x,    const float* __restrict__ emb,
    const float* __restrict__ Wih0, const float* __restrict__ Whh0,
    const float* __restrict__ bih0, const float* __restrict__ bhh0,
    const float* __restrict__ Wih1, const float* __restrict__ Whh1,
    const float* __restrict__ bih1, const float* __restrict__ bhh1,
    const float* __restrict__ Wfc,  const float* __restrict__ bfc,
    float* __restrict__ out, int* __restrict__ bar,
    float4* __restrict__ A0, float4* __restrict__ A1,
    float4* __restrict__ B0, float4* __restrict__ B1,
    const float4* __restrict__ xe4, int use_xe)
{
  __shared__ float4 wlds[3072];
  const int tid  = threadIdx.x;
  const int wg   = blockIdx.x;
  const int lane = tid & 63;
  const int wave = tid >> 6;
  const bool isL1 = (wg >= 128);
  const int j0   = (isL1 ? wg - 128 : wg) * 4;
  const int kin4 = isL1 ? 128 : 64;

  stage_weights(wlds, tid, j0, kin4, isL1 ? Wih1 : Wih0, isL1 ? Whh1 : Whh0);
  __syncthreads();

  const int j = j0 + wave;
  const float* bih = isL1 ? bih1 : bih0;
  const float* bhh = isL1 ? bhh1 : bhh0;
  const float br  = bih[j]        + bhh[j];
  const float bz  = bih[j + 512]  + bhh[j + 512];
  const float bnx = bih[j + 1024];
  const float bnh = bhh[j + 1024];

  const float4* w0 = &wlds[(wave * 3 + 0) * 256];
  const float4* w1 = &wlds[(wave * 3 + 1) * 256];
  const float4* w2 = &wlds[(wave * 3 + 2) * 256];

  float4* A[2] = {A0, A1};
  float4* B[2] = {B0, B1};

  for (int t = 0; t <= S_LEN; ++t){
    if (!isL1){
      if (t < S_LEN){
        const float4* hprev = A[(t + 1) & 1];
        float ar = br, az = bz, anx = bnx, anh = bnh;
        if (use_xe) accum_vec(xe4 + (size_t)t * 4096, w0, w1, w2, 64, lane, ar, az, anx);
        else        accum_emb(x, emb, t, w0, w1, w2, lane, ar, az, anx);
        accum_vec(hprev, w0 + 64, w1 + 64, w2 + 64, 128, lane, ar, az, anh);
        finish_store(hprev, ar, az, anx, anh, lane, j, A[t & 1]);
      }
    } else if (t >= 1){
      const int u = t - 1;
      const float4* xin   = A[u & 1];
      const float4* hprev = B[(u + 1) & 1];
      float ar = br, az = bz, anx = bnx, anh = bnh;
      accum_vec(xin,   w0,       w1,       w2,       128, lane, ar, az, anx);
      accum_vec(hprev, w0 + 128, w1 + 128, w2 + 128, 128, lane, ar, az, anh);
      finish_store(hprev, ar, az, anx, anh, lane, j, B[u & 1]);
    }
    barrier_tick(bar, wg, tid, t);
  }

  if (wg == 0 && wave == 0){
    float acc = bfc[0];
    const float4* h1 = B[1];
    const float4* wf = (const float4*)Wfc;
    #pragma unroll 4
    for (int k = 0; k < 128; ++k){
      float4 hv = h1[k * 64 + lane];
      float4 wv = wf[k];
      acc = fmaf(hv.x, wv.x, acc); acc = fmaf(hv.y, wv.y, acc);
      acc = fmaf(hv.z, wv.z, acc); acc = fmaf(hv.w, wv.w, acc);
    }
    out[lane] = sigmoid_f(acc);
  }
}

extern "C" void kernel_launch(void* const* d_in, const int* in_sizes, int n_in,
                              void* d_out, int out_size, void* d_ws, size_t ws_size,
                              hipStream_t stream)
{
  (void)in_sizes; (void)n_in; (void)out_size;
  const int*   x    = (const int*)  d_in[0];
  const float* emb  = (const float*)d_in[1];
  const float* Wih0 = (const float*)d_in[2];
  const float* Whh0 = (const float*)d_in[3];
  const float* bih0 = (const float*)d_in[4];
  const float* bhh0 = (const float*)d_in[5];
  const float* Wih1 = (const float*)d_in[6];
  const float* Whh1 = (const float*)d_in[7];
  const float* bih1 = (const float*)d_in[8];
  const float* bhh1 = (const float*)d_in[9];
  const float* Wfc  = (const float*)d_in[10];
  const float* bfc  = (const float*)d_in[11];
  float* out = (float*)d_out;
  char* ws = (char*)d_ws;

  if (ws_size >= (size_t)NEED_FAST){
    // no sync memset needed: tagged records self-validate against 0xAA poison
    wcvt_kernel<<<2752512 / TPB, TPB, 0, stream>>>(Wih0, Whh0, Wih1, Whh1, ws);
    gather_xe_bf_kernel<<<2097152 / TPB, TPB, 0, stream>>>(x, emb, ws);
    gru_mfma_kernel<<<128, TPB, 0, stream>>>(bih0, bhh0, bih1, bhh1, Wfc, bfc, out, ws);
  } else {
    int*    bar = (int*)ws;
    float4* A0  = (float4*)(ws + A_OFF);
    float4* A1  = (float4*)(ws + A_OFF + HBUF_BYTES);
    float4* B0  = (float4*)(ws + B_OFF);
    float4* B1  = (float4*)(ws + B_OFF + HBUF_BYTES);
    float4* xe4 = (float4*)(ws + XE_OFF);
    const int use_xe = (ws_size >= (size_t)XE_OFF + XE_BYTES) ? 1 : 0;
    hipMemsetAsync(ws, 0, XE_OFF, stream);
    if (use_xe){
      gather_xe_kernel<<<(S_LEN * 64 * BATCH) / TPB, TPB, 0, stream>>>(x, emb, xe4);
    }
    gru_persist_kernel<<<256, TPB, 0, stream>>>(
        x, emb, Wih0, Whh0, bih0, bhh0, Wih1, Whh1, bih1, bhh1, Wfc, bfc,
        out, bar, A0, A1, B0, B1, xe4, use_xe);
  }
}